// Round 5
// baseline (333.480 us; speedup 1.0000x reference)
//
#include <hip/hip_runtime.h>
#include <string.h>
#include <math.h>

typedef unsigned short u16;
typedef __bf16 bf16x8 __attribute__((ext_vector_type(8)));
typedef float floatx4 __attribute__((ext_vector_type(4)));

#define HEADS  16
#define DH     64
#define BATCH  2
#define NQ     512
#define NKV    4096
#define DMODEL 1024
#define INNER  1024
#define SCALE  0.125f
#define LOG2E  1.4426950408889634f

__device__ __forceinline__ u16 f2bf(float f) {
  union { float f; unsigned int u; } v; v.f = f;
  unsigned int u = v.u;
  unsigned int r = u + 0x7fffu + ((u >> 16) & 1u);   // RNE
  return (u16)(r >> 16);
}

// async global->LDS, 16B per lane; LDS dest = wave-uniform base + lane*16
__device__ __forceinline__ void gll16(const u16* g, u16* l) {
  __builtin_amdgcn_global_load_lds(
      (const __attribute__((address_space(1))) unsigned int*)g,
      (__attribute__((address_space(3))) unsigned int*)l, 16, 0, 0);
}

// ---------------- fp32 -> bf16 convert, 8 elems/thread ----------------
__global__ __launch_bounds__(256) void conv_bf16(const float* __restrict__ x,
                                                 u16* __restrict__ y) {
  const size_t i = (size_t)blockIdx.x * 256 + threadIdx.x;
  const float4* p = (const float4*)x + i * 2;
  float4 a = p[0], b = p[1];
  union { u16 s[8]; uint4 q; } o;
  o.s[0] = f2bf(a.x); o.s[1] = f2bf(a.y); o.s[2] = f2bf(a.z); o.s[3] = f2bf(a.w);
  o.s[4] = f2bf(b.x); o.s[5] = f2bf(b.y); o.s[6] = f2bf(b.z); o.s[7] = f2bf(b.w);
  *(uint4*)(y + i * 8) = o.q;
}

// ---------------- transpose+convert: Wt[n][k] = bf16(W[k][n]), W is KxN ----
__global__ __launch_bounds__(256) void transpose_conv(const float* __restrict__ W,
                                                      u16* __restrict__ Wt,
                                                      int K, int N) {
  __shared__ float tile[32][33];
  const int tx = threadIdx.x & 31, ty = threadIdx.x >> 5;  // 32x8
  const int n0 = blockIdx.x * 32, k0 = blockIdx.y * 32;
  for (int i = 0; i < 32; i += 8)
    tile[ty + i][tx] = W[(size_t)(k0 + ty + i) * N + n0 + tx];
  __syncthreads();
  for (int i = 0; i < 32; i += 8)
    Wt[(size_t)(n0 + ty + i) * K + k0 + tx] = f2bf(tile[tx][ty + i]);
}

// ---------------- GEMM 128x128: C[MxN] = A[MxK](bf16) * Bt[NxK]^T ----------
template<bool OUT_BF16>
__global__ __launch_bounds__(256) void gemm_bt(const u16* __restrict__ A,
                                               const u16* __restrict__ Bt,
                                               float* __restrict__ Cf,
                                               u16* __restrict__ Cb,
                                               const float* __restrict__ bias,
                                               int M, int N, int K) {
  __shared__ __align__(16) u16 As[128 * 32];
  __shared__ __align__(16) u16 Bs[128 * 32];
  const int tid  = threadIdx.x;
  const int lane = tid & 63, wave = tid >> 6;
  const int wr = wave >> 1, wc = wave & 1;
  const int l16 = lane & 15, quad = lane >> 4;
  const int bm = blockIdx.y, bn = blockIdx.x;
  const int r0 = tid >> 2;
  const int kb = (tid & 3) ^ ((tid >> 3) & 3);     // swizzled k-block
  const u16* aP0 = A  + ((size_t)bm * 128 + r0)      * K + kb * 8;
  const u16* aP1 = A  + ((size_t)bm * 128 + r0 + 64) * K + kb * 8;
  const u16* bP0 = Bt + ((size_t)bn * 128 + r0)      * K + kb * 8;
  const u16* bP1 = Bt + ((size_t)bn * 128 + r0 + 64) * K + kb * 8;
  u16* ldsA0 = As + wave * 512;
  u16* ldsA1 = As + 2048 + wave * 512;
  u16* ldsB0 = Bs + wave * 512;
  u16* ldsB1 = Bs + 2048 + wave * 512;
  const int ko = ((quad ^ ((l16 >> 1) & 3)) << 3);

  floatx4 acc[4][4] = {};
  for (int k0 = 0; k0 < K; k0 += 32) {
    gll16(aP0 + k0, ldsA0);
    gll16(aP1 + k0, ldsA1);
    gll16(bP0 + k0, ldsB0);
    gll16(bP1 + k0, ldsB1);
    __syncthreads();
    bf16x8 af[4], bfr[4];
#pragma unroll
    for (int i = 0; i < 4; ++i)
      af[i] = *(const bf16x8*)&As[(wr * 64 + i * 16 + l16) * 32 + ko];
#pragma unroll
    for (int j = 0; j < 4; ++j)
      bfr[j] = *(const bf16x8*)&Bs[(wc * 64 + j * 16 + l16) * 32 + ko];
#pragma unroll
    for (int i = 0; i < 4; ++i)
#pragma unroll
      for (int j = 0; j < 4; ++j)
        acc[i][j] = __builtin_amdgcn_mfma_f32_16x16x32_bf16(af[i], bfr[j], acc[i][j], 0, 0, 0);
    __syncthreads();
  }
#pragma unroll
  for (int i = 0; i < 4; ++i) {
    const int rowb = bm * 128 + wr * 64 + i * 16 + quad * 4;
#pragma unroll
    for (int j = 0; j < 4; ++j) {
      const int col = bn * 128 + wc * 64 + j * 16 + l16;
#pragma unroll
      for (int r = 0; r < 4; ++r) {
        const size_t idx = (size_t)(rowb + r) * N + col;
        if (OUT_BF16) Cb[idx] = f2bf(acc[i][j][r]);
        else          Cf[idx] = acc[i][j][r] + bias[col];
      }
    }
  }
}

// ---------------- GEMM 64x64 tile (for small M,N: more blocks) ----------
template<bool OUT_BF16>
__global__ __launch_bounds__(256) void gemm64(const u16* __restrict__ A,
                                              const u16* __restrict__ Bt,
                                              float* __restrict__ Cf,
                                              u16* __restrict__ Cb,
                                              const float* __restrict__ bias,
                                              int M, int N, int K) {
  __shared__ __align__(16) u16 As[64 * 64];
  __shared__ __align__(16) u16 Bs[64 * 64];
  const int tid = threadIdx.x;
  const int lane = tid & 63, wave = tid >> 6;
  const int wr = wave >> 1, wc = wave & 1;
  const int l16 = lane & 15, quad = lane >> 4;
  const int bm = blockIdx.y, bn = blockIdx.x;
  const int r0 = tid >> 3;
  const int kbs = (tid & 7) ^ (r0 & 7);
  const u16* aP0 = A  + ((size_t)bm * 64 + r0)      * K + kbs * 8;
  const u16* aP1 = A  + ((size_t)bm * 64 + r0 + 32) * K + kbs * 8;
  const u16* bP0 = Bt + ((size_t)bn * 64 + r0)      * K + kbs * 8;
  const u16* bP1 = Bt + ((size_t)bn * 64 + r0 + 32) * K + kbs * 8;
  u16* ldsA0 = As + wave * 512;
  u16* ldsA1 = As + 2048 + wave * 512;
  u16* ldsB0 = Bs + wave * 512;
  u16* ldsB1 = Bs + 2048 + wave * 512;

  floatx4 acc[2][2] = {};
  for (int k0 = 0; k0 < K; k0 += 64) {
    gll16(aP0 + k0, ldsA0);
    gll16(aP1 + k0, ldsA1);
    gll16(bP0 + k0, ldsB0);
    gll16(bP1 + k0, ldsB1);
    __syncthreads();
    bf16x8 af[2][2], bfr[2][2];
#pragma unroll
    for (int i = 0; i < 2; ++i)
#pragma unroll
      for (int kk = 0; kk < 2; ++kk)
        af[i][kk] = *(const bf16x8*)&As[(wr * 32 + i * 16 + l16) * 64 +
                                        (((kk * 4 + quad) ^ (l16 & 7)) << 3)];
#pragma unroll
    for (int j = 0; j < 2; ++j)
#pragma unroll
      for (int kk = 0; kk < 2; ++kk)
        bfr[j][kk] = *(const bf16x8*)&Bs[(wc * 32 + j * 16 + l16) * 64 +
                                         (((kk * 4 + quad) ^ (l16 & 7)) << 3)];
#pragma unroll
    for (int i = 0; i < 2; ++i)
#pragma unroll
      for (int j = 0; j < 2; ++j) {
        acc[i][j] = __builtin_amdgcn_mfma_f32_16x16x32_bf16(af[i][0], bfr[j][0], acc[i][j], 0, 0, 0);
        acc[i][j] = __builtin_amdgcn_mfma_f32_16x16x32_bf16(af[i][1], bfr[j][1], acc[i][j], 0, 0, 0);
      }
    __syncthreads();
  }
#pragma unroll
  for (int i = 0; i < 2; ++i) {
    const int rowb = bm * 64 + wr * 32 + i * 16 + quad * 4;
#pragma unroll
    for (int j = 0; j < 2; ++j) {
      const int col = bn * 64 + wc * 32 + j * 16 + l16;
#pragma unroll
      for (int r = 0; r < 4; ++r) {
        const size_t idx = (size_t)(rowb + r) * N + col;
        if (OUT_BF16) Cb[idx] = f2bf(acc[i][j][r]);
        else          Cf[idx] = acc[i][j][r] + bias[col];
      }
    }
  }
}

// ---------------- flash attention: barrier-free wave pipelines -----------
// block = 128 thr = 2 waves, both on the SAME 16 queries; wave w owns keys
// [w*2048, w*2048+2048). Q/K fragments load direct global->VGPR (16B/lane);
// V and P use wave-PRIVATE LDS slabs (no __syncthreads in the main loop).
// Final 2-wave merge via LDS replaces split-K + combine.
__global__ __launch_bounds__(128, 2) void attn_wave(const u16* __restrict__ Qh,
                                                    const u16* __restrict__ KVp,
                                                    const int* __restrict__ mask,
                                                    u16* __restrict__ Out) {
  __shared__ __align__(16) u16 VsA[2][64 * 68];  // per-wave V^T slab (d x key)
  __shared__ __align__(16) u16 PsA[2][16 * 76];  // per-wave P tile
  __shared__ float Mw[32], Lw[32];
  const int tid = threadIdx.x, lane = tid & 63, w = tid >> 6;
  const int l16 = lane & 15, quad = lane >> 4;
  const int grp = blockIdx.x & 31;         // b*16+h ; same-grp blocks 32 apart -> same XCD
  const int qt  = blockIdx.x >> 5;         // 0..31 (16-query tiles)
  const int b = grp >> 4, h = grp & 15;
  u16* Vs = VsA[w];
  u16* Ps = PsA[w];
  const size_t kvstride = 2 * INNER;

  // Q fragments: A[m=l16][k=quad*8+j], direct from global
  const u16* qrow = Qh + ((size_t)(b * NQ + qt * 16 + l16)) * INNER + h * DH + quad * 8;
  bf16x8 aq0 = *(const bf16x8*)qrow;
  bf16x8 aq1 = *(const bf16x8*)(qrow + 32);

  floatx4 o[4] = {};
  float m_r[4] = {-1e30f, -1e30f, -1e30f, -1e30f};
  float l_r[4] = {0.f, 0.f, 0.f, 0.f};

  const int keyw = w * (NKV / 2);
  for (int c = 0; c < (NKV / 2) / 64; ++c) {
    const int key0 = keyw + c * 64;
    // ---- V loads: lane covers keys 4*l16..+3, d = quad*16..+15 ----
    union { uint4 q[2]; u16 s[16]; } vk[4];
    const u16* vb = KVp + ((size_t)(b * NKV + key0 + 4 * l16)) * kvstride + INNER + h * DH + quad * 16;
#pragma unroll
    for (int j = 0; j < 4; ++j) {
      vk[j].q[0] = *(const uint4*)(vb + (size_t)j * kvstride);
      vk[j].q[1] = *(const uint4*)(vb + (size_t)j * kvstride + 8);
    }
    // ---- K fragments direct global: B[n=key=l16][k=quad*8+j] ----
    bf16x8 bk0[4], bk1[4];
#pragma unroll
    for (int nt = 0; nt < 4; ++nt) {
      const u16* kr = KVp + ((size_t)(b * NKV + key0 + nt * 16 + l16)) * kvstride + h * DH + quad * 8;
      bk0[nt] = *(const bf16x8*)kr;
      bk1[nt] = *(const bf16x8*)(kr + 32);
    }
    float mk[4];
#pragma unroll
    for (int nt = 0; nt < 4; ++nt)
      mk[nt] = (mask[(size_t)b * NKV + key0 + nt * 16 + l16] != 0) ? 0.0f : -1e30f;

    // ---- V transpose into wave-private LDS (b64 packed, 8B aligned) ----
#pragma unroll
    for (int i = 0; i < 16; ++i) {
      union { u16 s[4]; uint2 d; } pk;
      pk.s[0] = vk[0].s[i]; pk.s[1] = vk[1].s[i];
      pk.s[2] = vk[2].s[i]; pk.s[3] = vk[3].s[i];
      *(uint2*)&Vs[(quad * 16 + i) * 68 + 4 * l16] = pk.d;
    }

    // ---- S = Q K^T (16 q x 64 keys) ----
    float sv[4][4];
#pragma unroll
    for (int nt = 0; nt < 4; ++nt) {
      floatx4 t = {0.f, 0.f, 0.f, 0.f};
      t = __builtin_amdgcn_mfma_f32_16x16x32_bf16(aq0, bk0[nt], t, 0, 0, 0);
      t = __builtin_amdgcn_mfma_f32_16x16x32_bf16(aq1, bk1[nt], t, 0, 0, 0);
#pragma unroll
      for (int r = 0; r < 4; ++r) sv[nt][r] = t[r] * (SCALE * LOG2E) + mk[nt];
    }
    // ---- row stats (row q = quad*4+r, spread over 16 lanes) ----
    float mnew[4], alpha[4], psum[4];
#pragma unroll
    for (int r = 0; r < 4; ++r) {
      float t = fmaxf(fmaxf(sv[0][r], sv[1][r]), fmaxf(sv[2][r], sv[3][r]));
      t = fmaxf(t, __shfl_xor(t, 1));
      t = fmaxf(t, __shfl_xor(t, 2));
      t = fmaxf(t, __shfl_xor(t, 4));
      t = fmaxf(t, __shfl_xor(t, 8));
      mnew[r] = fmaxf(m_r[r], t);
      alpha[r] = exp2f(m_r[r] - mnew[r]);
      m_r[r] = mnew[r];
      psum[r] = 0.f;
    }
    // ---- P = 2^(S-m) -> wave-private Ps, row sums ----
#pragma unroll
    for (int nt = 0; nt < 4; ++nt)
#pragma unroll
      for (int r = 0; r < 4; ++r) {
        float p = exp2f(sv[nt][r] - mnew[r]);
        psum[r] += p;
        Ps[(quad * 4 + r) * 76 + nt * 16 + l16] = f2bf(p);
      }
#pragma unroll
    for (int r = 0; r < 4; ++r) {
      float t = psum[r];
      t += __shfl_xor(t, 1);
      t += __shfl_xor(t, 2);
      t += __shfl_xor(t, 4);
      t += __shfl_xor(t, 8);
      l_r[r] = l_r[r] * alpha[r] + t;
#pragma unroll
      for (int dt = 0; dt < 4; ++dt) o[dt][r] *= alpha[r];
    }
    // ---- O += P V (P via LDS A-layout; V^T via LDS B-layout) ----
    bf16x8 ap0 = *(const bf16x8*)&Ps[l16 * 76 + quad * 8];
    bf16x8 ap1 = *(const bf16x8*)&Ps[l16 * 76 + 32 + quad * 8];
#pragma unroll
    for (int dt = 0; dt < 4; ++dt) {
      bf16x8 bv0 = *(const bf16x8*)&Vs[(dt * 16 + l16) * 68 + quad * 8];
      bf16x8 bv1 = *(const bf16x8*)&Vs[(dt * 16 + l16) * 68 + 32 + quad * 8];
      o[dt] = __builtin_amdgcn_mfma_f32_16x16x32_bf16(ap0, bv0, o[dt], 0, 0, 0);
      o[dt] = __builtin_amdgcn_mfma_f32_16x16x32_bf16(ap1, bv1, o[dt], 0, 0, 0);
    }
  }

  // ---- 2-wave merge (replaces split-K combine) ----
  __syncthreads();                       // all waves done with Vs/Ps
  if (l16 == 0) {
#pragma unroll
    for (int r = 0; r < 4; ++r) {
      Mw[w * 16 + quad * 4 + r] = m_r[r];
      Lw[w * 16 + quad * 4 + r] = l_r[r];
    }
  }
  float* Ob = (float*)&VsA[0][0];        // 32 rows x stride 68 fp32 (8.7KB, fits)
#pragma unroll
  for (int r = 0; r < 4; ++r)
#pragma unroll
    for (int dt = 0; dt < 4; ++dt)
      Ob[(w * 16 + quad * 4 + r) * 68 + dt * 16 + l16] = o[dt][r];
  __syncthreads();
  // wave w writes d-range [w*32, w*32+32)
#pragma unroll
  for (int r = 0; r < 4; ++r) {
    const int q = quad * 4 + r;
    const float m0 = Mw[q], m1 = Mw[16 + q];
    const float M = fmaxf(m0, m1);
    const float w0 = exp2f(m0 - M), w1 = exp2f(m1 - M);
    const float inv = 1.0f / (w0 * Lw[q] + w1 * Lw[16 + q]);
#pragma unroll
    for (int db = 0; db < 2; ++db) {
      const int d = w * 32 + db * 16 + l16;
      const float v = w0 * Ob[q * 68 + d] + w1 * Ob[(16 + q) * 68 + d];
      Out[((size_t)(b * NQ + qt * 16 + q)) * INNER + h * DH + d] = f2bf(v * inv);
    }
  }
}

// ---------------- launcher ----------------
extern "C" void kernel_launch(void* const* d_in, const int* in_sizes, int n_in,
                              void* d_out, int out_size, void* d_ws, size_t ws_size,
                              hipStream_t stream) {
  const float* q    = (const float*)d_in[0];
  const float* kv   = (const float*)d_in[1];
  const int*   mask = (const int*)d_in[2];
  const float* Wq   = (const float*)d_in[3];
  const float* Wkv  = (const float*)d_in[4];
  const float* Wo   = (const float*)d_in[5];
  const float* bo   = (const float*)d_in[6];
  float* out = (float*)d_out;

  char* ws = (char*)d_ws;
  u16* qb   = (u16*)(ws);                        // 2MB
  u16* kvb  = (u16*)(ws + (2u  << 20));          // 16MB
  u16* Wqt  = (u16*)(ws + (18u << 20));
  u16* Wkvt = (u16*)(ws + (20u << 20));
  u16* Wot  = (u16*)(ws + (24u << 20));
  u16* qh   = (u16*)(ws + (26u << 20));
  u16* kvp  = (u16*)(ws + (28u << 20));          // 32MB
  u16* attn = (u16*)(ws + (60u << 20));

  conv_bf16<<<dim3((BATCH * NQ * DMODEL) / 2048), 256, 0, stream>>>(q, qb);
  conv_bf16<<<dim3((BATCH * NKV * DMODEL) / 2048), 256, 0, stream>>>(kv, kvb);
  transpose_conv<<<dim3(INNER / 32, DMODEL / 32), 256, 0, stream>>>(Wq, Wqt, DMODEL, INNER);
  transpose_conv<<<dim3(2 * INNER / 32, DMODEL / 32), 256, 0, stream>>>(Wkv, Wkvt, DMODEL, 2 * INNER);
  transpose_conv<<<dim3(DMODEL / 32, INNER / 32), 256, 0, stream>>>(Wo, Wot, INNER, DMODEL);

  // qh = qb @ Wq (1024x1024x1024)
  gemm64<true><<<dim3(INNER / 64, (BATCH * NQ) / 64), 256, 0, stream>>>(
      qb, Wqt, nullptr, qh, nullptr, BATCH * NQ, INNER, DMODEL);
  // kvp = kvb @ Wkv (8192x2048x1024)
  gemm_bt<true><<<dim3((2 * INNER) / 128, (BATCH * NKV) / 128), 256, 0, stream>>>(
      kvb, Wkvt, nullptr, kvp, nullptr, BATCH * NKV, 2 * INNER, DMODEL);
  // attention: barrier-free wave pipelines, fused merge
  attn_wave<<<dim3((NQ / 16) * 32), 128, 0, stream>>>(qh, kvp, mask, attn);
  // out = attn @ Wo + bo (fp32)
  gemm64<false><<<dim3(DMODEL / 64, (BATCH * NQ) / 64), 256, 0, stream>>>(
      attn, Wot, out, nullptr, bo, BATCH * NQ, DMODEL, INNER);
}

// Round 6
// 269.703 us; speedup vs baseline: 1.2365x; 1.2365x over previous
//
#include <hip/hip_runtime.h>
#include <string.h>
#include <math.h>

typedef unsigned short u16;
typedef __bf16 bf16x8 __attribute__((ext_vector_type(8)));
typedef float floatx4 __attribute__((ext_vector_type(4)));

#define HEADS  16
#define DH     64
#define BATCH  2
#define NQ     512
#define NKV    4096
#define DMODEL 1024
#define INNER  1024
#define SCALE  0.125f
#define LOG2E  1.4426950408889634f
#define SPLIT  8
#define KEYS_PER_PART (NKV / SPLIT)
#define CH (KEYS_PER_PART / 64)

__device__ __forceinline__ u16 f2bf(float f) {
  union { float f; unsigned int u; } v; v.f = f;
  unsigned int u = v.u;
  unsigned int r = u + 0x7fffu + ((u >> 16) & 1u);   // RNE
  return (u16)(r >> 16);
}

// async global->LDS, 16B per lane
__device__ __forceinline__ void gll16(const u16* g, u16* l) {
  __builtin_amdgcn_global_load_lds(
      (const __attribute__((address_space(1))) unsigned int*)g,
      (__attribute__((address_space(3))) unsigned int*)l, 16, 0, 0);
}

// ---------------- fused prep: conv q, conv kv, transpose Wq/Wkv/Wo --------
__global__ __launch_bounds__(256) void prep(const float* __restrict__ q,
                                            const float* __restrict__ kv,
                                            const float* __restrict__ Wq,
                                            const float* __restrict__ Wkv,
                                            const float* __restrict__ Wo,
                                            u16* __restrict__ qb,
                                            u16* __restrict__ kvb,
                                            u16* __restrict__ Wqt,
                                            u16* __restrict__ Wkvt,
                                            u16* __restrict__ Wot) {
  __shared__ float tile[32][33];
  const int bx = blockIdx.x, tid = threadIdx.x;
  if (bx < 4608) {           // conv paths: 512 blocks q, 4096 blocks kv
    const float* x; u16* y; size_t i;
    if (bx < 512) { x = q;  y = qb;  i = (size_t)bx * 256 + tid; }
    else          { x = kv; y = kvb; i = (size_t)(bx - 512) * 256 + tid; }
    const float4* p = (const float4*)x + i * 2;
    float4 a = p[0], b = p[1];
    union { u16 s[8]; uint4 v; } o;
    o.s[0] = f2bf(a.x); o.s[1] = f2bf(a.y); o.s[2] = f2bf(a.z); o.s[3] = f2bf(a.w);
    o.s[4] = f2bf(b.x); o.s[5] = f2bf(b.y); o.s[6] = f2bf(b.z); o.s[7] = f2bf(b.w);
    *(uint4*)(y + i * 8) = o.v;
    return;
  }
  // transpose paths: Wt[n][k] = bf16(W[k][n])
  const float* W; u16* Wt; int K, N, n0, k0, t;
  if (bx < 5632)      { t = bx - 4608; W = Wq;  Wt = Wqt;  K = 1024; N = 1024; n0 = (t & 31) * 32; k0 = (t >> 5) * 32; }
  else if (bx < 7680) { t = bx - 5632; W = Wkv; Wt = Wkvt; K = 1024; N = 2048; n0 = (t & 63) * 32; k0 = (t >> 6) * 32; }
  else                { t = bx - 7680; W = Wo;  Wt = Wot;  K = 1024; N = 1024; n0 = (t & 31) * 32; k0 = (t >> 5) * 32; }
  const int tx = tid & 31, ty = tid >> 5;
  for (int i = 0; i < 32; i += 8)
    tile[ty + i][tx] = W[(size_t)(k0 + ty + i) * N + n0 + tx];
  __syncthreads();
  for (int i = 0; i < 32; i += 8)
    Wt[(size_t)(n0 + ty + i) * K + k0 + tx] = f2bf(tile[tx][ty + i]);
}

// ---------------- GEMM 128x128: C[MxN] = A[MxK](bf16) * Bt[NxK]^T ----------
template<bool OUT_BF16>
__global__ __launch_bounds__(256) void gemm_bt(const u16* __restrict__ A,
                                               const u16* __restrict__ Bt,
                                               float* __restrict__ Cf,
                                               u16* __restrict__ Cb,
                                               const float* __restrict__ bias,
                                               int M, int N, int K) {
  __shared__ __align__(16) u16 As[128 * 32];
  __shared__ __align__(16) u16 Bs[128 * 32];
  const int tid  = threadIdx.x;
  const int lane = tid & 63, wave = tid >> 6;
  const int wr = wave >> 1, wc = wave & 1;
  const int l16 = lane & 15, quad = lane >> 4;
  const int bm = blockIdx.y, bn = blockIdx.x;
  const int r0 = tid >> 2;
  const int kb = (tid & 3) ^ ((tid >> 3) & 3);
  const u16* aP0 = A  + ((size_t)bm * 128 + r0)      * K + kb * 8;
  const u16* aP1 = A  + ((size_t)bm * 128 + r0 + 64) * K + kb * 8;
  const u16* bP0 = Bt + ((size_t)bn * 128 + r0)      * K + kb * 8;
  const u16* bP1 = Bt + ((size_t)bn * 128 + r0 + 64) * K + kb * 8;
  u16* ldsA0 = As + wave * 512;
  u16* ldsA1 = As + 2048 + wave * 512;
  u16* ldsB0 = Bs + wave * 512;
  u16* ldsB1 = Bs + 2048 + wave * 512;
  const int ko = ((quad ^ ((l16 >> 1) & 3)) << 3);

  floatx4 acc[4][4] = {};
  for (int k0 = 0; k0 < K; k0 += 32) {
    gll16(aP0 + k0, ldsA0);
    gll16(aP1 + k0, ldsA1);
    gll16(bP0 + k0, ldsB0);
    gll16(bP1 + k0, ldsB1);
    __syncthreads();
    bf16x8 af[4], bfr[4];
#pragma unroll
    for (int i = 0; i < 4; ++i)
      af[i] = *(const bf16x8*)&As[(wr * 64 + i * 16 + l16) * 32 + ko];
#pragma unroll
    for (int j = 0; j < 4; ++j)
      bfr[j] = *(const bf16x8*)&Bs[(wc * 64 + j * 16 + l16) * 32 + ko];
#pragma unroll
    for (int i = 0; i < 4; ++i)
#pragma unroll
      for (int j = 0; j < 4; ++j)
        acc[i][j] = __builtin_amdgcn_mfma_f32_16x16x32_bf16(af[i], bfr[j], acc[i][j], 0, 0, 0);
    __syncthreads();
  }
#pragma unroll
  for (int i = 0; i < 4; ++i) {
    const int rowb = bm * 128 + wr * 64 + i * 16 + quad * 4;
#pragma unroll
    for (int j = 0; j < 4; ++j) {
      const int col = bn * 128 + wc * 64 + j * 16 + l16;
#pragma unroll
      for (int r = 0; r < 4; ++r) {
        const size_t idx = (size_t)(rowb + r) * N + col;
        if (OUT_BF16) Cb[idx] = f2bf(acc[i][j][r]);
        else          Cf[idx] = acc[i][j][r] + bias[col];
      }
    }
  }
}

// ---------------- GEMM 64x64 tile (for small M,N) ----------
template<bool OUT_BF16>
__global__ __launch_bounds__(256) void gemm64(const u16* __restrict__ A,
                                              const u16* __restrict__ Bt,
                                              float* __restrict__ Cf,
                                              u16* __restrict__ Cb,
                                              const float* __restrict__ bias,
                                              int M, int N, int K) {
  __shared__ __align__(16) u16 As[64 * 64];
  __shared__ __align__(16) u16 Bs[64 * 64];
  const int tid = threadIdx.x;
  const int lane = tid & 63, wave = tid >> 6;
  const int wr = wave >> 1, wc = wave & 1;
  const int l16 = lane & 15, quad = lane >> 4;
  const int bm = blockIdx.y, bn = blockIdx.x;
  const int r0 = tid >> 3;
  const int kbs = (tid & 7) ^ (r0 & 7);
  const u16* aP0 = A  + ((size_t)bm * 64 + r0)      * K + kbs * 8;
  const u16* aP1 = A  + ((size_t)bm * 64 + r0 + 32) * K + kbs * 8;
  const u16* bP0 = Bt + ((size_t)bn * 64 + r0)      * K + kbs * 8;
  const u16* bP1 = Bt + ((size_t)bn * 64 + r0 + 32) * K + kbs * 8;
  u16* ldsA0 = As + wave * 512;
  u16* ldsA1 = As + 2048 + wave * 512;
  u16* ldsB0 = Bs + wave * 512;
  u16* ldsB1 = Bs + 2048 + wave * 512;

  floatx4 acc[2][2] = {};
  for (int k0 = 0; k0 < K; k0 += 64) {
    gll16(aP0 + k0, ldsA0);
    gll16(aP1 + k0, ldsA1);
    gll16(bP0 + k0, ldsB0);
    gll16(bP1 + k0, ldsB1);
    __syncthreads();
    bf16x8 af[2][2], bfr[2][2];
#pragma unroll
    for (int i = 0; i < 2; ++i)
#pragma unroll
      for (int kk = 0; kk < 2; ++kk)
        af[i][kk] = *(const bf16x8*)&As[(wr * 32 + i * 16 + l16) * 64 +
                                        (((kk * 4 + quad) ^ (l16 & 7)) << 3)];
#pragma unroll
    for (int j = 0; j < 2; ++j)
#pragma unroll
      for (int kk = 0; kk < 2; ++kk)
        bfr[j][kk] = *(const bf16x8*)&Bs[(wc * 32 + j * 16 + l16) * 64 +
                                         (((kk * 4 + quad) ^ (l16 & 7)) << 3)];
#pragma unroll
    for (int i = 0; i < 2; ++i)
#pragma unroll
      for (int j = 0; j < 2; ++j) {
        acc[i][j] = __builtin_amdgcn_mfma_f32_16x16x32_bf16(af[i][0], bfr[j][0], acc[i][j], 0, 0, 0);
        acc[i][j] = __builtin_amdgcn_mfma_f32_16x16x32_bf16(af[i][1], bfr[j][1], acc[i][j], 0, 0, 0);
      }
    __syncthreads();
  }
#pragma unroll
  for (int i = 0; i < 2; ++i) {
    const int rowb = bm * 64 + wr * 32 + i * 16 + quad * 4;
#pragma unroll
    for (int j = 0; j < 2; ++j) {
      const int col = bn * 64 + wc * 32 + j * 16 + l16;
#pragma unroll
      for (int r = 0; r < 4; ++r) {
        const size_t idx = (size_t)(rowb + r) * N + col;
        if (OUT_BF16) Cb[idx] = f2bf(acc[i][j][r]);
        else          Cf[idx] = acc[i][j][r] + bias[col];
      }
    }
  }
}

// ---------------- flash attention split-K partials, Q-tile 128 ----------
// 4 waves; wave w owns q rows [w*32, w*32+32) as two 16-row MFMA tiles.
// blockIdx = (((b*16+h)*4+qt)*8)+part -> consecutive parts on different XCDs,
// each XCD sees a disjoint 512-key KV slice (4 MB = one XCD L2).
__global__ __launch_bounds__(256, 4) void attn_part(const u16* __restrict__ Qh,
                                                    const u16* __restrict__ KVp,
                                                    const int* __restrict__ mask,
                                                    _Float16* __restrict__ Opart,
                                                    float* __restrict__ Mst,
                                                    float* __restrict__ Lst) {
  __shared__ __align__(16) u16 Ks[64 * 72];
  __shared__ __align__(16) u16 Vs[64 * 68];   // V^T: [d][key]
  __shared__ __align__(16) u16 QP[9728];      // Q(128x72) then Ps(4 waves x 32 x 76)
  __shared__ float Msk[64];
  const int tid = threadIdx.x;
  const int lane = tid & 63, w = tid >> 6;
  const int l16 = lane & 15, quad = lane >> 4;
  const int bx = blockIdx.x;
  const int part = bx & 7;
  const int qt = (bx >> 3) & 3;
  const int h  = (bx >> 5) & 15;
  const int b  = bx >> 9;
  const int rs = tid >> 2, ck = (tid & 3) * 16;   // K/Q staging map
  const int kp = tid & 31, dh8 = tid >> 5;        // V staging: keys 2kp,2kp+1
  const size_t kvstride = 2 * INNER;
  u16* Ps = QP + w * 2432;                        // 32 rows * stride 76

  { // stage Q tile (128 x 64), stride 72
#pragma unroll
    for (int rr = 0; rr < 2; ++rr) {
      const int row = rr * 64 + rs;
      const uint4* p = (const uint4*)(Qh + ((size_t)(b * NQ + qt * 128 + row)) * INNER + h * DH + ck);
      *(uint4*)&QP[row * 72 + ck]     = p[0];
      *(uint4*)&QP[row * 72 + ck + 8] = p[1];
    }
  }
  __syncthreads();
  bf16x8 aq[2][2];
#pragma unroll
  for (int mi = 0; mi < 2; ++mi) {
    aq[mi][0] = *(const bf16x8*)&QP[(w * 32 + mi * 16 + l16) * 72 + quad * 8];
    aq[mi][1] = *(const bf16x8*)&QP[(w * 32 + mi * 16 + l16) * 72 + 32 + quad * 8];
  }
  __syncthreads();   // QP now reusable as Ps

  floatx4 o[2][4] = {};
  float m_r[2][4], l_r[2][4];
#pragma unroll
  for (int mi = 0; mi < 2; ++mi)
#pragma unroll
    for (int r = 0; r < 4; ++r) { m_r[mi][r] = -1e30f; l_r[mi][r] = 0.f; }

  const int key00 = part * KEYS_PER_PART;
  uint4 kr0, kr1, vr0, vr1;
  float mkreg = 0.f;
  auto preload = [&](int c) {
    const int key0 = key00 + c * 64;
    const u16* kb_ = KVp + ((size_t)(b * NKV + key0 + rs)) * kvstride + h * DH + ck;
    kr0 = ((const uint4*)kb_)[0];
    kr1 = ((const uint4*)kb_)[1];
    const u16* vb_ = KVp + ((size_t)(b * NKV + key0 + 2 * kp)) * kvstride + INNER + h * DH + dh8 * 8;
    vr0 = *(const uint4*)vb_;
    vr1 = *(const uint4*)(vb_ + kvstride);
    if (tid < 64) mkreg = (mask[(size_t)b * NKV + key0 + tid] != 0) ? 0.0f : -1e30f;
  };
  preload(0);

  for (int c = 0; c < CH; ++c) {
    __syncthreads();   // all waves done reading previous Ks/Vs
    *(uint4*)&Ks[rs * 72 + ck]     = kr0;
    *(uint4*)&Ks[rs * 72 + ck + 8] = kr1;
    {
      union { uint4 v; u16 s[8]; } a, bb;
      a.v = vr0; bb.v = vr1;
#pragma unroll
      for (int i = 0; i < 8; ++i) {
        unsigned int pack = (unsigned int)a.s[i] | ((unsigned int)bb.s[i] << 16);
        *(unsigned int*)&Vs[(dh8 * 8 + i) * 68 + 2 * kp] = pack;
      }
    }
    if (tid < 64) Msk[tid] = mkreg;
    __syncthreads();
    if (c + 1 < CH) preload(c + 1);   // overlaps the compute below

    // ---- per 16-row m-tile: S, softmax, P ----
#pragma unroll
    for (int mi = 0; mi < 2; ++mi) {
      float sv[4][4];
#pragma unroll
      for (int nt = 0; nt < 4; ++nt) {
        bf16x8 b0 = *(const bf16x8*)&Ks[(nt * 16 + l16) * 72 + quad * 8];
        bf16x8 b1 = *(const bf16x8*)&Ks[(nt * 16 + l16) * 72 + 32 + quad * 8];
        floatx4 t = {0.f, 0.f, 0.f, 0.f};
        t = __builtin_amdgcn_mfma_f32_16x16x32_bf16(aq[mi][0], b0, t, 0, 0, 0);
        t = __builtin_amdgcn_mfma_f32_16x16x32_bf16(aq[mi][1], b1, t, 0, 0, 0);
        const float mk = Msk[nt * 16 + l16];
#pragma unroll
        for (int r = 0; r < 4; ++r) sv[nt][r] = t[r] * (SCALE * LOG2E) + mk;
      }
      float mnew[4], alpha[4], psum[4];
#pragma unroll
      for (int r = 0; r < 4; ++r) {
        float t = fmaxf(fmaxf(sv[0][r], sv[1][r]), fmaxf(sv[2][r], sv[3][r]));
        t = fmaxf(t, __shfl_xor(t, 1));
        t = fmaxf(t, __shfl_xor(t, 2));
        t = fmaxf(t, __shfl_xor(t, 4));
        t = fmaxf(t, __shfl_xor(t, 8));
        mnew[r] = fmaxf(m_r[mi][r], t);
        alpha[r] = exp2f(m_r[mi][r] - mnew[r]);
        m_r[mi][r] = mnew[r];
        psum[r] = 0.f;
      }
#pragma unroll
      for (int nt = 0; nt < 4; ++nt)
#pragma unroll
        for (int r = 0; r < 4; ++r) {
          float p = exp2f(sv[nt][r] - mnew[r]);
          psum[r] += p;
          Ps[(mi * 16 + quad * 4 + r) * 76 + nt * 16 + l16] = f2bf(p);
        }
#pragma unroll
      for (int r = 0; r < 4; ++r) {
        float t = psum[r];
        t += __shfl_xor(t, 1);
        t += __shfl_xor(t, 2);
        t += __shfl_xor(t, 4);
        t += __shfl_xor(t, 8);
        l_r[mi][r] = l_r[mi][r] * alpha[r] + t;
#pragma unroll
        for (int dt = 0; dt < 4; ++dt) o[mi][dt][r] *= alpha[r];
      }
    }
    // ---- O += P V ----
#pragma unroll
    for (int mi = 0; mi < 2; ++mi) {
      bf16x8 ap0 = *(const bf16x8*)&Ps[(mi * 16 + l16) * 76 + quad * 8];
      bf16x8 ap1 = *(const bf16x8*)&Ps[(mi * 16 + l16) * 76 + 32 + quad * 8];
#pragma unroll
      for (int dt = 0; dt < 4; ++dt) {
        bf16x8 bv0 = *(const bf16x8*)&Vs[(dt * 16 + l16) * 68 + quad * 8];
        bf16x8 bv1 = *(const bf16x8*)&Vs[(dt * 16 + l16) * 68 + 32 + quad * 8];
        o[mi][dt] = __builtin_amdgcn_mfma_f32_16x16x32_bf16(ap0, bv0, o[mi][dt], 0, 0, 0);
        o[mi][dt] = __builtin_amdgcn_mfma_f32_16x16x32_bf16(ap1, bv1, o[mi][dt], 0, 0, 0);
      }
    }
  }
  // ---- epilogue: fp16 partial O + (m,l) stats (log2 domain) ----
#pragma unroll
  for (int mi = 0; mi < 2; ++mi)
#pragma unroll
    for (int r = 0; r < 4; ++r) {
      const int qloc = w * 32 + mi * 16 + quad * 4 + r;
      if (l16 == 0) {
        Mst[(size_t)bx * 128 + qloc] = m_r[mi][r];
        Lst[(size_t)bx * 128 + qloc] = l_r[mi][r];
      }
#pragma unroll
      for (int dt = 0; dt < 4; ++dt)
        Opart[(size_t)bx * 8192 + qloc * 64 + dt * 16 + l16] = (_Float16)o[mi][dt][r];
    }
}

// ---------------- combine split-K partials + bf16 store ----------------
// grid 128 = (b,h,qt128); thread t: q = t>>1 (0..127), d-half = (t&1)*32
__global__ __launch_bounds__(256) void attn_combine(const _Float16* __restrict__ Opart,
                                                    const float* __restrict__ Mst,
                                                    const float* __restrict__ Lst,
                                                    u16* __restrict__ Out) {
  const int x = blockIdx.x, t = threadIdx.x;
  const int q = t >> 1, dh2 = (t & 1) * 32;
  const int b = x >> 6, h = (x >> 2) & 15, qt = x & 3;
  const int pid0 = x * SPLIT;
  float ms[SPLIT], ls[SPLIT];
#pragma unroll
  for (int s = 0; s < SPLIT; ++s) {
    ms[s] = Mst[(size_t)(pid0 + s) * 128 + q];
    ls[s] = Lst[(size_t)(pid0 + s) * 128 + q];
  }
  float M = ms[0];
#pragma unroll
  for (int s = 1; s < SPLIT; ++s) M = fmaxf(M, ms[s]);
  float wgt[SPLIT], L = 0.f;
#pragma unroll
  for (int s = 0; s < SPLIT; ++s) { wgt[s] = exp2f(ms[s] - M); L += wgt[s] * ls[s]; }
  const float inv = 1.0f / L;
  float acc[32] = {};
#pragma unroll
  for (int s = 0; s < SPLIT; ++s) {
    const _Float16* p = Opart + (size_t)(pid0 + s) * 8192 + q * 64 + dh2;
    const float ws = wgt[s];
#pragma unroll
    for (int i = 0; i < 32; ++i) acc[i] += ws * (float)p[i];
  }
  union { u16 s[32]; uint4 v[4]; } ou;
#pragma unroll
  for (int i = 0; i < 32; ++i) ou.s[i] = f2bf(acc[i] * inv);
  u16* dst = Out + ((size_t)(b * NQ + qt * 128 + q)) * INNER + h * DH + dh2;
#pragma unroll
  for (int i = 0; i < 4; ++i) *(uint4*)(dst + i * 8) = ou.v[i];
}

// ---------------- launcher ----------------
extern "C" void kernel_launch(void* const* d_in, const int* in_sizes, int n_in,
                              void* d_out, int out_size, void* d_ws, size_t ws_size,
                              hipStream_t stream) {
  const float* q    = (const float*)d_in[0];
  const float* kv   = (const float*)d_in[1];
  const int*   mask = (const int*)d_in[2];
  const float* Wq   = (const float*)d_in[3];
  const float* Wkv  = (const float*)d_in[4];
  const float* Wo   = (const float*)d_in[5];
  const float* bo   = (const float*)d_in[6];
  float* out = (float*)d_out;

  char* ws = (char*)d_ws;
  // low region: qb/kvb live through the projection GEMMs, then reused
  u16*      qb    = (u16*)(ws);                      // 2MB
  u16*      kvb   = (u16*)(ws + (2u << 20));         // 16MB
  float*    Mst   = (float*)(ws);                    // 512KB (aliases qb)
  float*    Lst   = (float*)(ws + (512u << 10));     // 512KB (aliases qb)
  _Float16* Opart = (_Float16*)(ws + (1u << 20));    // 16MB  (aliases qb tail+kvb)
  u16* Wqt  = (u16*)(ws + (18u << 20));
  u16* Wkvt = (u16*)(ws + (20u << 20));
  u16* Wot  = (u16*)(ws + (24u << 20));
  u16* qh   = (u16*)(ws + (26u << 20));
  u16* kvp  = (u16*)(ws + (28u << 20));              // 32MB
  u16* attn = (u16*)(ws + (60u << 20));

  // fused conversions + weight transposes (1 launch instead of 5)
  prep<<<dim3(8704), 256, 0, stream>>>(q, kv, Wq, Wkv, Wo, qb, kvb, Wqt, Wkvt, Wot);
  // qh = qb @ Wq (1024x1024x1024)
  gemm64<true><<<dim3(INNER / 64, (BATCH * NQ) / 64), 256, 0, stream>>>(
      qb, Wqt, nullptr, qh, nullptr, BATCH * NQ, INNER, DMODEL);
  // kvp = kvb @ Wkv (8192x2048x1024)
  gemm_bt<true><<<dim3((2 * INNER) / 128, (BATCH * NQ * 8) / 128), 256, 0, stream>>>(
      kvb, Wkvt, nullptr, kvp, nullptr, BATCH * NKV, 2 * INNER, DMODEL);
  // attention: split-K partials (Q-tile 128) + combine
  attn_part<<<dim3(BATCH * HEADS * (NQ / 128) * SPLIT), 256, 0, stream>>>(
      qh, kvp, mask, Opart, Mst, Lst);
  attn_combine<<<dim3(BATCH * HEADS * (NQ / 128)), 256, 0, stream>>>(Opart, Mst, Lst, attn);
  // out = attn @ Wo + bo (fp32)
  gemm64<false><<<dim3(DMODEL / 64, (BATCH * NQ) / 64), 256, 0, stream>>>(
      attn, Wot, out, nullptr, bo, BATCH * NQ, DMODEL, INNER);
}

// Round 7
// 255.465 us; speedup vs baseline: 1.3054x; 1.0557x over previous
//
#include <hip/hip_runtime.h>
#include <string.h>
#include <math.h>

typedef unsigned short u16;
typedef __bf16 bf16x8 __attribute__((ext_vector_type(8)));
typedef float floatx4 __attribute__((ext_vector_type(4)));

#define HEADS  16
#define DH     64
#define BATCH  2
#define NQ     512
#define NKV    4096
#define DMODEL 1024
#define INNER  1024
#define SCALE  0.125f
#define LOG2E  1.4426950408889634f
#define SPLIT  4
#define KEYS_PER_PART (NKV / SPLIT)
#define CH (KEYS_PER_PART / 64)

__device__ __forceinline__ u16 f2bf(float f) {
  union { float f; unsigned int u; } v; v.f = f;
  unsigned int u = v.u;
  unsigned int r = u + 0x7fffu + ((u >> 16) & 1u);   // RNE
  return (u16)(r >> 16);
}

// async global->LDS, 16B per lane
__device__ __forceinline__ void gll16(const u16* g, u16* l) {
  __builtin_amdgcn_global_load_lds(
      (const __attribute__((address_space(1))) unsigned int*)g,
      (__attribute__((address_space(3))) unsigned int*)l, 16, 0, 0);
}

// ---------------- fused prep: conv q, conv kv, transpose Wq/Wkv/Wo --------
__global__ __launch_bounds__(256) void prep(const float* __restrict__ q,
                                            const float* __restrict__ kv,
                                            const float* __restrict__ Wq,
                                            const float* __restrict__ Wkv,
                                            const float* __restrict__ Wo,
                                            u16* __restrict__ qb,
                                            u16* __restrict__ kvb,
                                            u16* __restrict__ Wqt,
                                            u16* __restrict__ Wkvt,
                                            u16* __restrict__ Wot) {
  __shared__ float tile[32][33];
  const int bx = blockIdx.x, tid = threadIdx.x;
  if (bx < 4608) {           // conv paths: 512 blocks q, 4096 blocks kv
    const float* x; u16* y; size_t i;
    if (bx < 512) { x = q;  y = qb;  i = (size_t)bx * 256 + tid; }
    else          { x = kv; y = kvb; i = (size_t)(bx - 512) * 256 + tid; }
    const float4* p = (const float4*)x + i * 2;
    float4 a = p[0], b = p[1];
    union { u16 s[8]; uint4 v; } o;
    o.s[0] = f2bf(a.x); o.s[1] = f2bf(a.y); o.s[2] = f2bf(a.z); o.s[3] = f2bf(a.w);
    o.s[4] = f2bf(b.x); o.s[5] = f2bf(b.y); o.s[6] = f2bf(b.z); o.s[7] = f2bf(b.w);
    *(uint4*)(y + i * 8) = o.v;
    return;
  }
  // transpose paths: Wt[n][k] = bf16(W[k][n])
  const float* W; u16* Wt; int K, N, n0, k0, t;
  if (bx < 5632)      { t = bx - 4608; W = Wq;  Wt = Wqt;  K = 1024; N = 1024; n0 = (t & 31) * 32; k0 = (t >> 5) * 32; }
  else if (bx < 7680) { t = bx - 5632; W = Wkv; Wt = Wkvt; K = 1024; N = 2048; n0 = (t & 63) * 32; k0 = (t >> 6) * 32; }
  else                { t = bx - 7680; W = Wo;  Wt = Wot;  K = 1024; N = 1024; n0 = (t & 31) * 32; k0 = (t >> 5) * 32; }
  const int tx = tid & 31, ty = tid >> 5;
  for (int i = 0; i < 32; i += 8)
    tile[ty + i][tx] = W[(size_t)(k0 + ty + i) * N + n0 + tx];
  __syncthreads();
  for (int i = 0; i < 32; i += 8)
    Wt[(size_t)(n0 + ty + i) * K + k0 + tx] = f2bf(tile[tx][ty + i]);
}

// ---------------- GEMM 128x128: C[MxN] = A[MxK](bf16) * Bt[NxK]^T ----------
template<bool OUT_BF16>
__global__ __launch_bounds__(256) void gemm_bt(const u16* __restrict__ A,
                                               const u16* __restrict__ Bt,
                                               float* __restrict__ Cf,
                                               u16* __restrict__ Cb,
                                               const float* __restrict__ bias,
                                               int M, int N, int K) {
  __shared__ __align__(16) u16 As[128 * 32];
  __shared__ __align__(16) u16 Bs[128 * 32];
  const int tid  = threadIdx.x;
  const int lane = tid & 63, wave = tid >> 6;
  const int wr = wave >> 1, wc = wave & 1;
  const int l16 = lane & 15, quad = lane >> 4;
  const int bm = blockIdx.y, bn = blockIdx.x;
  const int r0 = tid >> 2;
  const int kb = (tid & 3) ^ ((tid >> 3) & 3);
  const u16* aP0 = A  + ((size_t)bm * 128 + r0)      * K + kb * 8;
  const u16* aP1 = A  + ((size_t)bm * 128 + r0 + 64) * K + kb * 8;
  const u16* bP0 = Bt + ((size_t)bn * 128 + r0)      * K + kb * 8;
  const u16* bP1 = Bt + ((size_t)bn * 128 + r0 + 64) * K + kb * 8;
  u16* ldsA0 = As + wave * 512;
  u16* ldsA1 = As + 2048 + wave * 512;
  u16* ldsB0 = Bs + wave * 512;
  u16* ldsB1 = Bs + 2048 + wave * 512;
  const int ko = ((quad ^ ((l16 >> 1) & 3)) << 3);

  floatx4 acc[4][4] = {};
  for (int k0 = 0; k0 < K; k0 += 32) {
    gll16(aP0 + k0, ldsA0);
    gll16(aP1 + k0, ldsA1);
    gll16(bP0 + k0, ldsB0);
    gll16(bP1 + k0, ldsB1);
    __syncthreads();
    bf16x8 af[4], bfr[4];
#pragma unroll
    for (int i = 0; i < 4; ++i)
      af[i] = *(const bf16x8*)&As[(wr * 64 + i * 16 + l16) * 32 + ko];
#pragma unroll
    for (int j = 0; j < 4; ++j)
      bfr[j] = *(const bf16x8*)&Bs[(wc * 64 + j * 16 + l16) * 32 + ko];
#pragma unroll
    for (int i = 0; i < 4; ++i)
#pragma unroll
      for (int j = 0; j < 4; ++j)
        acc[i][j] = __builtin_amdgcn_mfma_f32_16x16x32_bf16(af[i], bfr[j], acc[i][j], 0, 0, 0);
    __syncthreads();
  }
#pragma unroll
  for (int i = 0; i < 4; ++i) {
    const int rowb = bm * 128 + wr * 64 + i * 16 + quad * 4;
#pragma unroll
    for (int j = 0; j < 4; ++j) {
      const int col = bn * 128 + wc * 64 + j * 16 + l16;
#pragma unroll
      for (int r = 0; r < 4; ++r) {
        const size_t idx = (size_t)(rowb + r) * N + col;
        if (OUT_BF16) Cb[idx] = f2bf(acc[i][j][r]);
        else          Cf[idx] = acc[i][j][r] + bias[col];
      }
    }
  }
}

// ---------------- GEMM 64x64 tile (for small M,N) ----------
template<bool OUT_BF16>
__global__ __launch_bounds__(256) void gemm64(const u16* __restrict__ A,
                                              const u16* __restrict__ Bt,
                                              float* __restrict__ Cf,
                                              u16* __restrict__ Cb,
                                              const float* __restrict__ bias,
                                              int M, int N, int K) {
  __shared__ __align__(16) u16 As[64 * 64];
  __shared__ __align__(16) u16 Bs[64 * 64];
  const int tid = threadIdx.x;
  const int lane = tid & 63, wave = tid >> 6;
  const int wr = wave >> 1, wc = wave & 1;
  const int l16 = lane & 15, quad = lane >> 4;
  const int bm = blockIdx.y, bn = blockIdx.x;
  const int r0 = tid >> 3;
  const int kbs = (tid & 7) ^ (r0 & 7);
  const u16* aP0 = A  + ((size_t)bm * 64 + r0)      * K + kbs * 8;
  const u16* aP1 = A  + ((size_t)bm * 64 + r0 + 32) * K + kbs * 8;
  const u16* bP0 = Bt + ((size_t)bn * 64 + r0)      * K + kbs * 8;
  const u16* bP1 = Bt + ((size_t)bn * 64 + r0 + 32) * K + kbs * 8;
  u16* ldsA0 = As + wave * 512;
  u16* ldsA1 = As + 2048 + wave * 512;
  u16* ldsB0 = Bs + wave * 512;
  u16* ldsB1 = Bs + 2048 + wave * 512;

  floatx4 acc[2][2] = {};
  for (int k0 = 0; k0 < K; k0 += 64) {
    gll16(aP0 + k0, ldsA0);
    gll16(aP1 + k0, ldsA1);
    gll16(bP0 + k0, ldsB0);
    gll16(bP1 + k0, ldsB1);
    __syncthreads();
    bf16x8 af[2][2], bfr[2][2];
#pragma unroll
    for (int i = 0; i < 2; ++i)
#pragma unroll
      for (int kk = 0; kk < 2; ++kk)
        af[i][kk] = *(const bf16x8*)&As[(wr * 32 + i * 16 + l16) * 64 +
                                        (((kk * 4 + quad) ^ (l16 & 7)) << 3)];
#pragma unroll
    for (int j = 0; j < 2; ++j)
#pragma unroll
      for (int kk = 0; kk < 2; ++kk)
        bfr[j][kk] = *(const bf16x8*)&Bs[(wc * 32 + j * 16 + l16) * 64 +
                                         (((kk * 4 + quad) ^ (l16 & 7)) << 3)];
#pragma unroll
    for (int i = 0; i < 2; ++i)
#pragma unroll
      for (int j = 0; j < 2; ++j) {
        acc[i][j] = __builtin_amdgcn_mfma_f32_16x16x32_bf16(af[i][0], bfr[j][0], acc[i][j], 0, 0, 0);
        acc[i][j] = __builtin_amdgcn_mfma_f32_16x16x32_bf16(af[i][1], bfr[j][1], acc[i][j], 0, 0, 0);
      }
    __syncthreads();
  }
#pragma unroll
  for (int i = 0; i < 2; ++i) {
    const int rowb = bm * 64 + wr * 32 + i * 16 + quad * 4;
#pragma unroll
    for (int j = 0; j < 2; ++j) {
      const int col = bn * 64 + wc * 32 + j * 16 + l16;
#pragma unroll
      for (int r = 0; r < 4; ++r) {
        const size_t idx = (size_t)(rowb + r) * N + col;
        if (OUT_BF16) Cb[idx] = f2bf(acc[i][j][r]);
        else          Cf[idx] = acc[i][j][r] + bias[col];
      }
    }
  }
}

// ---------------- flash attention, split-K partials (R2 structure) --------
// 4 waves; block handles (b,h,64-q tile, 1024-key part); wave owns 16 q.
// Stage K/V/mask -> barrier -> compute -> barrier. fp32 partial output.
__global__ __launch_bounds__(256) void attn_part(const u16* __restrict__ Qh,
                                                 const u16* __restrict__ KVp,
                                                 const int* __restrict__ mask,
                                                 float* __restrict__ Opart,
                                                 float* __restrict__ Mst,
                                                 float* __restrict__ Lst) {
  __shared__ __align__(16) u16 Ks[64 * 72];
  __shared__ __align__(16) u16 Vs[64 * 72];   // V^T: [d][key]
  __shared__ __align__(16) u16 QP[4864];      // union: Qs(64x72) / Ps(4 x 16 x 76)
  __shared__ float Msk[64];
  const int tid = threadIdx.x;
  const int lane = tid & 63, w = tid >> 6;
  const int l16 = lane & 15, quad = lane >> 4;
  const int part = blockIdx.x & (SPLIT - 1);
  const int qt = (blockIdx.x >> 2) & 7;
  const int h  = (blockIdx.x >> 5) & 15;
  const int b  = blockIdx.x >> 9;
  const int rs = tid >> 2, d0 = (tid & 3) * 16;   // K/Q staging map
  const int kp = tid & 31, dh8 = tid >> 5;        // V staging: keys 2kp,2kp+1; d=dh8*8..+7
  const size_t kvstride = 2 * INNER;
  u16* Ps = QP + w * 1216;                        // 16 rows * stride 76

  { // stage Q tile (64 x 64), stride 72
    const uint4* p = (const uint4*)(Qh + ((size_t)(b * NQ + qt * 64 + rs)) * INNER + h * DH + d0);
    *(uint4*)&QP[rs * 72 + d0]     = p[0];
    *(uint4*)&QP[rs * 72 + d0 + 8] = p[1];
  }
  __syncthreads();
  bf16x8 aq0 = *(const bf16x8*)&QP[(w * 16 + l16) * 72 + quad * 8];
  bf16x8 aq1 = *(const bf16x8*)&QP[(w * 16 + l16) * 72 + 32 + quad * 8];
  __syncthreads();   // QP now reusable as Ps

  floatx4 o[4] = {};
  float m_r[4] = {-1e30f, -1e30f, -1e30f, -1e30f};
  float l_r[4] = {0.f, 0.f, 0.f, 0.f};

  for (int c = 0; c < CH; ++c) {
    const int key0 = part * KEYS_PER_PART + c * 64;
    { // ---- stage K (rows, stride 72), V (transposed, packed b32), mask ----
      const u16* kbase = KVp + ((size_t)(b * NKV + key0 + rs)) * kvstride + h * DH + d0;
      uint4 k0v = ((const uint4*)kbase)[0];
      uint4 k1v = ((const uint4*)kbase)[1];
      *(uint4*)&Ks[rs * 72 + d0]     = k0v;
      *(uint4*)&Ks[rs * 72 + d0 + 8] = k1v;
      const u16* vbase = KVp + ((size_t)(b * NKV + key0 + 2 * kp)) * kvstride + INNER + h * DH + dh8 * 8;
      union { uint4 v; u16 s[8]; } va, vb;
      va.v = *(const uint4*)vbase;
      vb.v = *(const uint4*)(vbase + kvstride);
#pragma unroll
      for (int i = 0; i < 8; ++i) {
        unsigned int pack = (unsigned int)va.s[i] | ((unsigned int)vb.s[i] << 16);
        *(unsigned int*)&Vs[(dh8 * 8 + i) * 72 + 2 * kp] = pack;
      }
      if (tid < 64) Msk[tid] = (mask[(size_t)b * NKV + key0 + tid] != 0) ? 0.0f : -1e30f;
    }
    __syncthreads();

    // ---- S = Q K^T (16 q x 64 keys per wave) ----
    float sv[4][4];
#pragma unroll
    for (int nt = 0; nt < 4; ++nt) {
      bf16x8 b0 = *(const bf16x8*)&Ks[(nt * 16 + l16) * 72 + quad * 8];
      bf16x8 b1 = *(const bf16x8*)&Ks[(nt * 16 + l16) * 72 + 32 + quad * 8];
      floatx4 t = {0.f, 0.f, 0.f, 0.f};
      t = __builtin_amdgcn_mfma_f32_16x16x32_bf16(aq0, b0, t, 0, 0, 0);
      t = __builtin_amdgcn_mfma_f32_16x16x32_bf16(aq1, b1, t, 0, 0, 0);
      const float mk = Msk[nt * 16 + l16];
#pragma unroll
      for (int r = 0; r < 4; ++r) sv[nt][r] = t[r] * (SCALE * LOG2E) + mk;  // log2 domain
    }
    // ---- row stats (row = quad*4+r across 16 lanes of the quad) ----
    float mnew[4], alpha[4], psum[4];
#pragma unroll
    for (int r = 0; r < 4; ++r) {
      float t = fmaxf(fmaxf(sv[0][r], sv[1][r]), fmaxf(sv[2][r], sv[3][r]));
      t = fmaxf(t, __shfl_xor(t, 1));
      t = fmaxf(t, __shfl_xor(t, 2));
      t = fmaxf(t, __shfl_xor(t, 4));
      t = fmaxf(t, __shfl_xor(t, 8));
      mnew[r] = fmaxf(m_r[r], t);
      alpha[r] = exp2f(m_r[r] - mnew[r]);
      m_r[r] = mnew[r];
      psum[r] = 0.f;
    }
    // ---- P = 2^(S-m) -> Ps (stride 76), row sums ----
#pragma unroll
    for (int nt = 0; nt < 4; ++nt)
#pragma unroll
      for (int r = 0; r < 4; ++r) {
        float p = exp2f(sv[nt][r] - mnew[r]);
        psum[r] += p;
        Ps[(quad * 4 + r) * 76 + nt * 16 + l16] = f2bf(p);
      }
#pragma unroll
    for (int r = 0; r < 4; ++r) {
      float t = psum[r];
      t += __shfl_xor(t, 1);
      t += __shfl_xor(t, 2);
      t += __shfl_xor(t, 4);
      t += __shfl_xor(t, 8);
      l_r[r] = l_r[r] * alpha[r] + t;
#pragma unroll
      for (int dt = 0; dt < 4; ++dt) o[dt][r] *= alpha[r];
    }
    // ---- O += P V ----
    bf16x8 ap0 = *(const bf16x8*)&Ps[l16 * 76 + quad * 8];
    bf16x8 ap1 = *(const bf16x8*)&Ps[l16 * 76 + 32 + quad * 8];
#pragma unroll
    for (int dt = 0; dt < 4; ++dt) {
      bf16x8 bv0 = *(const bf16x8*)&Vs[(dt * 16 + l16) * 72 + quad * 8];
      bf16x8 bv1 = *(const bf16x8*)&Vs[(dt * 16 + l16) * 72 + 32 + quad * 8];
      o[dt] = __builtin_amdgcn_mfma_f32_16x16x32_bf16(ap0, bv0, o[dt], 0, 0, 0);
      o[dt] = __builtin_amdgcn_mfma_f32_16x16x32_bf16(ap1, bv1, o[dt], 0, 0, 0);
    }
    __syncthreads();
  }
  // ---- epilogue: fp32 unnormalized partial O + (m,l) stats ----
  const int pid = blockIdx.x;
#pragma unroll
  for (int r = 0; r < 4; ++r) {
    const int q = w * 16 + quad * 4 + r;
    if (l16 == 0) { Mst[pid * 64 + q] = m_r[r]; Lst[pid * 64 + q] = l_r[r]; }
#pragma unroll
    for (int dt = 0; dt < 4; ++dt)
      Opart[(size_t)pid * 4096 + q * 64 + dt * 16 + l16] = o[dt][r];
  }
}

// ---------------- combine split-K partials ----------------
__global__ __launch_bounds__(256) void attn_combine(const float* __restrict__ Opart,
                                                    const float* __restrict__ Mst,
                                                    const float* __restrict__ Lst,
                                                    u16* __restrict__ Out) {
  const int x = blockIdx.x;
  const int t = threadIdx.x;
  const int q = t >> 2, db = (t & 3) * 16;
  const int b = x >> 7, h = (x >> 3) & 15, qt = x & 7;
  float ms[SPLIT], ls[SPLIT];
#pragma unroll
  for (int s = 0; s < SPLIT; ++s) {
    ms[s] = Mst[(size_t)(x * SPLIT + s) * 64 + q];
    ls[s] = Lst[(size_t)(x * SPLIT + s) * 64 + q];
  }
  float M = fmaxf(fmaxf(ms[0], ms[1]), fmaxf(ms[2], ms[3]));
  float wgt[SPLIT], L = 0.f;
#pragma unroll
  for (int s = 0; s < SPLIT; ++s) { wgt[s] = exp2f(ms[s] - M); L += wgt[s] * ls[s]; }
  const float inv = 1.0f / L;
  float acc[16] = {};
#pragma unroll
  for (int s = 0; s < SPLIT; ++s) {
    const float4* p = (const float4*)&Opart[(size_t)(x * SPLIT + s) * 4096 + q * 64 + db];
    const float ws = wgt[s];
#pragma unroll
    for (int i = 0; i < 4; ++i) {
      float4 v = p[i];
      acc[i * 4 + 0] += ws * v.x; acc[i * 4 + 1] += ws * v.y;
      acc[i * 4 + 2] += ws * v.z; acc[i * 4 + 3] += ws * v.w;
    }
  }
  union { u16 s[16]; uint4 v[2]; } ou;
#pragma unroll
  for (int i = 0; i < 16; ++i) ou.s[i] = f2bf(acc[i] * inv);
  u16* dst = Out + ((size_t)(b * NQ + qt * 64 + q)) * INNER + h * DH + db;
  *(uint4*)dst = ou.v[0]; *(uint4*)(dst + 8) = ou.v[1];
}

// ---------------- launcher ----------------
extern "C" void kernel_launch(void* const* d_in, const int* in_sizes, int n_in,
                              void* d_out, int out_size, void* d_ws, size_t ws_size,
                              hipStream_t stream) {
  const float* q    = (const float*)d_in[0];
  const float* kv   = (const float*)d_in[1];
  const int*   mask = (const int*)d_in[2];
  const float* Wq   = (const float*)d_in[3];
  const float* Wkv  = (const float*)d_in[4];
  const float* Wo   = (const float*)d_in[5];
  const float* bo   = (const float*)d_in[6];
  float* out = (float*)d_out;

  char* ws = (char*)d_ws;
  // low region: qb/kvb live through the projection GEMMs, then reused
  u16*   qb    = (u16*)(ws);                     // 2MB
  u16*   kvb   = (u16*)(ws + (2u << 20));        // 16MB
  float* Mst   = (float*)(ws);                   // 256KB (aliases qb)
  float* Lst   = (float*)(ws + (512u << 10));    // 256KB (aliases qb)
  float* Opart = (float*)(ws + (2u << 20));      // 16MB  (aliases kvb)
  u16* Wqt  = (u16*)(ws + (18u << 20));
  u16* Wkvt = (u16*)(ws + (20u << 20));
  u16* Wot  = (u16*)(ws + (24u << 20));
  u16* qh   = (u16*)(ws + (26u << 20));
  u16* kvp  = (u16*)(ws + (28u << 20));          // 32MB
  u16* attn = (u16*)(ws + (60u << 20));

  // fused conversions + weight transposes
  prep<<<dim3(8704), 256, 0, stream>>>(q, kv, Wq, Wkv, Wo, qb, kvb, Wqt, Wkvt, Wot);
  // qh = qb @ Wq (1024x1024x1024)
  gemm64<true><<<dim3(INNER / 64, (BATCH * NQ) / 64), 256, 0, stream>>>(
      qb, Wqt, nullptr, qh, nullptr, BATCH * NQ, INNER, DMODEL);
  // kvp = kvb @ Wkv (8192x2048x1024)
  gemm_bt<true><<<dim3((2 * INNER) / 128, (BATCH * NKV) / 128), 256, 0, stream>>>(
      kvb, Wkvt, nullptr, kvp, nullptr, BATCH * NKV, 2 * INNER, DMODEL);
  // attention: split-K partials (R2 structure) + combine
  attn_part<<<dim3(BATCH * HEADS * (NQ / 64) * SPLIT), 256, 0, stream>>>(
      qh, kvp, mask, Opart, Mst, Lst);
  attn_combine<<<dim3(BATCH * HEADS * (NQ / 64)), 256, 0, stream>>>(Opart, Mst, Lst, attn);
  // out = attn @ Wo + bo (fp32)
  gemm64<false><<<dim3(DMODEL / 64, (BATCH * NQ) / 64), 256, 0, stream>>>(
      attn, Wot, out, nullptr, bo, BATCH * NQ, DMODEL, INNER);
}

// Round 8
// 247.792 us; speedup vs baseline: 1.3458x; 1.0310x over previous
//
#include <hip/hip_runtime.h>
#include <string.h>
#include <math.h>

typedef unsigned short u16;
typedef __bf16 bf16x8 __attribute__((ext_vector_type(8)));
typedef float floatx4 __attribute__((ext_vector_type(4)));

#define HEADS  16
#define DH     64
#define BATCH  2
#define NQ     512
#define NKV    4096
#define DMODEL 1024
#define INNER  1024
#define SCALE  0.125f
#define LOG2E  1.4426950408889634f
#define SPLIT  4
#define KEYS_PER_PART (NKV / SPLIT)
#define CH (KEYS_PER_PART / 64)

__device__ __forceinline__ u16 f2bf(float f) {
  union { float f; unsigned int u; } v; v.f = f;
  unsigned int u = v.u;
  unsigned int r = u + 0x7fffu + ((u >> 16) & 1u);   // RNE
  return (u16)(r >> 16);
}

// async global->LDS, 16B per lane; LDS dest = wave-uniform base + lane*16
__device__ __forceinline__ void gll16(const u16* g, u16* l) {
  __builtin_amdgcn_global_load_lds(
      (const __attribute__((address_space(1))) unsigned int*)g,
      (__attribute__((address_space(3))) unsigned int*)l, 16, 0, 0);
}

// ---------------- fused prep: conv q, conv kv, transpose Wq/Wkv/Wo --------
__global__ __launch_bounds__(256) void prep(const float* __restrict__ q,
                                            const float* __restrict__ kv,
                                            const float* __restrict__ Wq,
                                            const float* __restrict__ Wkv,
                                            const float* __restrict__ Wo,
                                            u16* __restrict__ qb,
                                            u16* __restrict__ kvb,
                                            u16* __restrict__ Wqt,
                                            u16* __restrict__ Wkvt,
                                            u16* __restrict__ Wot) {
  __shared__ float tile[32][33];
  const int bx = blockIdx.x, tid = threadIdx.x;
  if (bx < 4608) {           // conv paths: 512 blocks q, 4096 blocks kv
    const float* x; u16* y; size_t i;
    if (bx < 512) { x = q;  y = qb;  i = (size_t)bx * 256 + tid; }
    else          { x = kv; y = kvb; i = (size_t)(bx - 512) * 256 + tid; }
    const float4* p = (const float4*)x + i * 2;
    float4 a = p[0], b = p[1];
    union { u16 s[8]; uint4 v; } o;
    o.s[0] = f2bf(a.x); o.s[1] = f2bf(a.y); o.s[2] = f2bf(a.z); o.s[3] = f2bf(a.w);
    o.s[4] = f2bf(b.x); o.s[5] = f2bf(b.y); o.s[6] = f2bf(b.z); o.s[7] = f2bf(b.w);
    *(uint4*)(y + i * 8) = o.v;
    return;
  }
  // transpose paths: Wt[n][k] = bf16(W[k][n])
  const float* W; u16* Wt; int K, N, n0, k0, t;
  if (bx < 5632)      { t = bx - 4608; W = Wq;  Wt = Wqt;  K = 1024; N = 1024; n0 = (t & 31) * 32; k0 = (t >> 5) * 32; }
  else if (bx < 7680) { t = bx - 5632; W = Wkv; Wt = Wkvt; K = 1024; N = 2048; n0 = (t & 63) * 32; k0 = (t >> 6) * 32; }
  else                { t = bx - 7680; W = Wo;  Wt = Wot;  K = 1024; N = 1024; n0 = (t & 31) * 32; k0 = (t >> 5) * 32; }
  const int tx = tid & 31, ty = tid >> 5;
  for (int i = 0; i < 32; i += 8)
    tile[ty + i][tx] = W[(size_t)(k0 + ty + i) * N + n0 + tx];
  __syncthreads();
  for (int i = 0; i < 32; i += 8)
    Wt[(size_t)(n0 + ty + i) * K + k0 + tx] = f2bf(tile[tx][ty + i]);
}

// ---------------- KV GEMM 128x128: writes K and V to separate buffers -----
// C[8192 x 2048] = A[8192x1024] * Wkvt[2048x1024]^T; bn<8 -> Kb, else Vb,
// both [token][1024].
__global__ __launch_bounds__(256) void gemm_kv(const u16* __restrict__ A,
                                               const u16* __restrict__ Bt,
                                               u16* __restrict__ Kb,
                                               u16* __restrict__ Vb) {
  const int K = DMODEL;
  __shared__ __align__(16) u16 As[128 * 32];
  __shared__ __align__(16) u16 Bs[128 * 32];
  const int tid  = threadIdx.x;
  const int lane = tid & 63, wave = tid >> 6;
  const int wr = wave >> 1, wc = wave & 1;
  const int l16 = lane & 15, quad = lane >> 4;
  const int bm = blockIdx.y, bn = blockIdx.x;
  const int r0 = tid >> 2;
  const int kb = (tid & 3) ^ ((tid >> 3) & 3);
  const u16* aP0 = A  + ((size_t)bm * 128 + r0)      * K + kb * 8;
  const u16* aP1 = A  + ((size_t)bm * 128 + r0 + 64) * K + kb * 8;
  const u16* bP0 = Bt + ((size_t)bn * 128 + r0)      * K + kb * 8;
  const u16* bP1 = Bt + ((size_t)bn * 128 + r0 + 64) * K + kb * 8;
  u16* ldsA0 = As + wave * 512;
  u16* ldsA1 = As + 2048 + wave * 512;
  u16* ldsB0 = Bs + wave * 512;
  u16* ldsB1 = Bs + 2048 + wave * 512;
  const int ko = ((quad ^ ((l16 >> 1) & 3)) << 3);

  floatx4 acc[4][4] = {};
  for (int k0 = 0; k0 < K; k0 += 32) {
    gll16(aP0 + k0, ldsA0);
    gll16(aP1 + k0, ldsA1);
    gll16(bP0 + k0, ldsB0);
    gll16(bP1 + k0, ldsB1);
    __syncthreads();
    bf16x8 af[4], bfr[4];
#pragma unroll
    for (int i = 0; i < 4; ++i)
      af[i] = *(const bf16x8*)&As[(wr * 64 + i * 16 + l16) * 32 + ko];
#pragma unroll
    for (int j = 0; j < 4; ++j)
      bfr[j] = *(const bf16x8*)&Bs[(wc * 64 + j * 16 + l16) * 32 + ko];
#pragma unroll
    for (int i = 0; i < 4; ++i)
#pragma unroll
      for (int j = 0; j < 4; ++j)
        acc[i][j] = __builtin_amdgcn_mfma_f32_16x16x32_bf16(af[i], bfr[j], acc[i][j], 0, 0, 0);
    __syncthreads();
  }
  u16* Cb = (bn < 8) ? Kb : Vb;
  const int colbase = ((bn < 8) ? bn : bn - 8) * 128;
#pragma unroll
  for (int i = 0; i < 4; ++i) {
    const int rowb = bm * 128 + wr * 64 + i * 16 + quad * 4;
#pragma unroll
    for (int j = 0; j < 4; ++j) {
      const int col = colbase + wc * 64 + j * 16 + l16;
#pragma unroll
      for (int r = 0; r < 4; ++r)
        Cb[(size_t)(rowb + r) * 1024 + col] = f2bf(acc[i][j][r]);
    }
  }
}

// ---------------- GEMM 64x64 tile (Q-proj / O-proj) ----------
template<bool OUT_BF16>
__global__ __launch_bounds__(256) void gemm64(const u16* __restrict__ A,
                                              const u16* __restrict__ Bt,
                                              float* __restrict__ Cf,
                                              u16* __restrict__ Cb,
                                              const float* __restrict__ bias,
                                              int M, int N, int K) {
  __shared__ __align__(16) u16 As[64 * 64];
  __shared__ __align__(16) u16 Bs[64 * 64];
  const int tid = threadIdx.x;
  const int lane = tid & 63, wave = tid >> 6;
  const int wr = wave >> 1, wc = wave & 1;
  const int l16 = lane & 15, quad = lane >> 4;
  const int bm = blockIdx.y, bn = blockIdx.x;
  const int r0 = tid >> 3;
  const int kbs = (tid & 7) ^ (r0 & 7);
  const u16* aP0 = A  + ((size_t)bm * 64 + r0)      * K + kbs * 8;
  const u16* aP1 = A  + ((size_t)bm * 64 + r0 + 32) * K + kbs * 8;
  const u16* bP0 = Bt + ((size_t)bn * 64 + r0)      * K + kbs * 8;
  const u16* bP1 = Bt + ((size_t)bn * 64 + r0 + 32) * K + kbs * 8;
  u16* ldsA0 = As + wave * 512;
  u16* ldsA1 = As + 2048 + wave * 512;
  u16* ldsB0 = Bs + wave * 512;
  u16* ldsB1 = Bs + 2048 + wave * 512;

  floatx4 acc[2][2] = {};
  for (int k0 = 0; k0 < K; k0 += 64) {
    gll16(aP0 + k0, ldsA0);
    gll16(aP1 + k0, ldsA1);
    gll16(bP0 + k0, ldsB0);
    gll16(bP1 + k0, ldsB1);
    __syncthreads();
    bf16x8 af[2][2], bfr[2][2];
#pragma unroll
    for (int i = 0; i < 2; ++i)
#pragma unroll
      for (int kk = 0; kk < 2; ++kk)
        af[i][kk] = *(const bf16x8*)&As[(wr * 32 + i * 16 + l16) * 64 +
                                        (((kk * 4 + quad) ^ (l16 & 7)) << 3)];
#pragma unroll
    for (int j = 0; j < 2; ++j)
#pragma unroll
      for (int kk = 0; kk < 2; ++kk)
        bfr[j][kk] = *(const bf16x8*)&Bs[(wc * 32 + j * 16 + l16) * 64 +
                                         (((kk * 4 + quad) ^ (l16 & 7)) << 3)];
#pragma unroll
    for (int i = 0; i < 2; ++i)
#pragma unroll
      for (int j = 0; j < 2; ++j) {
        acc[i][j] = __builtin_amdgcn_mfma_f32_16x16x32_bf16(af[i][0], bfr[j][0], acc[i][j], 0, 0, 0);
        acc[i][j] = __builtin_amdgcn_mfma_f32_16x16x32_bf16(af[i][1], bfr[j][1], acc[i][j], 0, 0, 0);
      }
    __syncthreads();
  }
#pragma unroll
  for (int i = 0; i < 2; ++i) {
    const int rowb = bm * 64 + wr * 32 + i * 16 + quad * 4;
#pragma unroll
    for (int j = 0; j < 2; ++j) {
      const int col = bn * 64 + wc * 32 + j * 16 + l16;
#pragma unroll
      for (int r = 0; r < 4; ++r) {
        const size_t idx = (size_t)(rowb + r) * N + col;
        if (OUT_BF16) Cb[idx] = f2bf(acc[i][j][r]);
        else          Cf[idx] = acc[i][j][r] + bias[col];
      }
    }
  }
}

// ---------------- V transpose: Vb[token][1024] -> vT[b][h][d][4096] -------
__global__ __launch_bounds__(256) void vtrans(const u16* __restrict__ Vb,
                                              u16* __restrict__ vT) {
  __shared__ u16 t[64 * 72];
  const int bx = blockIdx.x, tid = threadIdx.x;
  const int bh = bx >> 6, tb = bx & 63;      // bh = b*16+h, tb = 64-token block
  const int b = bh >> 4, h = bh & 15;
  const int r = tid >> 2, cg = (tid & 3) * 16;
  const u16* src = Vb + ((size_t)(b * NKV + tb * 64 + r)) * 1024 + h * 64 + cg;
  *(uint4*)&t[r * 72 + cg]     = ((const uint4*)src)[0];
  *(uint4*)&t[r * 72 + cg + 8] = ((const uint4*)src)[1];
  __syncthreads();
  const int d = tid >> 2, tg = (tid & 3) * 16;
  union { u16 s[16]; uint4 v[2]; } o;
#pragma unroll
  for (int i = 0; i < 16; ++i) o.s[i] = t[(tg + i) * 72 + d];
  u16* dst = vT + ((size_t)(bh * 64 + d)) * NKV + tb * 64 + tg;
  *(uint4*)dst = o.v[0]; *(uint4*)(dst + 8) = o.v[1];
}

// ---------------- flash attention, split-K partials (R2 + DMA staging) ----
// 4 waves; block = (b,h,64-q tile, 1024-key part); wave owns 16 q.
// K and V^T staged via global_load_lds width16 into unpadded 64x64 LDS with
// gemm-style XOR source swizzle. Zero staging VALU.
__global__ __launch_bounds__(256) void attn_part(const u16* __restrict__ Qh,
                                                 const u16* __restrict__ Kb,
                                                 const u16* __restrict__ vT,
                                                 const int* __restrict__ mask,
                                                 float* __restrict__ Opart,
                                                 float* __restrict__ Mst,
                                                 float* __restrict__ Lst) {
  __shared__ __align__(16) u16 Qs[64 * 72];
  __shared__ __align__(16) u16 Ks[64 * 64];
  __shared__ __align__(16) u16 Vs[64 * 64];   // V^T tile: [d][key]
  __shared__ __align__(16) u16 Ps[4][16 * 72];
  __shared__ float Msk[64];
  const int tid = threadIdx.x;
  const int lane = tid & 63, w = tid >> 6;
  const int l16 = lane & 15, quad = lane >> 4;
  const int part = blockIdx.x & (SPLIT - 1);
  const int qt = (blockIdx.x >> 2) & 7;
  const int h  = (blockIdx.x >> 5) & 15;
  const int b  = blockIdx.x >> 9;
  const int rs = tid >> 2, d0 = (tid & 3) * 16;

  { // stage Q tile (64 x 64), stride 72
    const uint4* p = (const uint4*)(Qh + ((size_t)(b * NQ + qt * 64 + rs)) * INNER + h * DH + d0);
    *(uint4*)&Qs[rs * 72 + d0]     = p[0];
    *(uint4*)&Qs[rs * 72 + d0 + 8] = p[1];
  }
  __syncthreads();
  bf16x8 aq0 = *(const bf16x8*)&Qs[(w * 16 + l16) * 72 + quad * 8];
  bf16x8 aq1 = *(const bf16x8*)&Qs[(w * 16 + l16) * 72 + 32 + quad * 8];

  // DMA source mapping: inst row = wave*8 + (lane>>3) (+32), k-block = (lane&7)^(lane>>3 &7)
  const int r8 = lane >> 3;
  const int kb8 = (lane & 7) ^ (r8 & 7);
  const int key00 = part * KEYS_PER_PART;
  const u16* kSrc = Kb + ((size_t)(b * NKV + key00 + w * 8 + r8)) * 1024 + h * DH + kb8 * 8;
  const u16* vSrc = vT + ((size_t)((b * 16 + h) * 64 + w * 8 + r8)) * NKV + key00 + kb8 * 8;
  u16* ldsK0 = Ks + w * 512;          // rows w*8..w*8+7
  u16* ldsK1 = Ks + 2048 + w * 512;   // rows 32+...
  u16* ldsV0 = Vs + w * 512;
  u16* ldsV1 = Vs + 2048 + w * 512;
  // read-side swizzled k-block offsets (row&7 == l16&7 for rows nt*16+l16)
  const int koA = (quad ^ (l16 & 7)) << 3;        // k-half 0
  const int koB = ((quad + 4) ^ (l16 & 7)) << 3;  // k-half 1

  floatx4 o[4] = {};
  float m_r[4] = {-1e30f, -1e30f, -1e30f, -1e30f};
  float l_r[4] = {0.f, 0.f, 0.f, 0.f};

  for (int c = 0; c < CH; ++c) {
    const int key0 = key00 + c * 64;
    // ---- DMA staging (prev chunk fully consumed at loop-end barrier) ----
    gll16(kSrc + (size_t)c * 65536, ldsK0);            // +64 tokens * 1024
    gll16(kSrc + (size_t)c * 65536 + 32768, ldsK1);    // +32 rows
    gll16(vSrc + c * 64, ldsV0);                       // +64 keys in-row
    gll16(vSrc + c * 64 + (size_t)32 * NKV, ldsV1);    // +32 d-rows
    if (tid < 64) Msk[tid] = (mask[(size_t)b * NKV + key0 + tid] != 0) ? 0.0f : -1e30f;
    __syncthreads();

    // ---- S = Q K^T (16 q x 64 keys per wave) ----
    float sv[4][4];
#pragma unroll
    for (int nt = 0; nt < 4; ++nt) {
      bf16x8 b0 = *(const bf16x8*)&Ks[(nt * 16 + l16) * 64 + koA];
      bf16x8 b1 = *(const bf16x8*)&Ks[(nt * 16 + l16) * 64 + koB];
      floatx4 t = {0.f, 0.f, 0.f, 0.f};
      t = __builtin_amdgcn_mfma_f32_16x16x32_bf16(aq0, b0, t, 0, 0, 0);
      t = __builtin_amdgcn_mfma_f32_16x16x32_bf16(aq1, b1, t, 0, 0, 0);
      const float mk = Msk[nt * 16 + l16];
#pragma unroll
      for (int r = 0; r < 4; ++r) sv[nt][r] = t[r] * (SCALE * LOG2E) + mk;  // log2 domain
    }
    // ---- row stats ----
    float mnew[4], alpha[4], psum[4];
#pragma unroll
    for (int r = 0; r < 4; ++r) {
      float t = fmaxf(fmaxf(sv[0][r], sv[1][r]), fmaxf(sv[2][r], sv[3][r]));
      t = fmaxf(t, __shfl_xor(t, 1));
      t = fmaxf(t, __shfl_xor(t, 2));
      t = fmaxf(t, __shfl_xor(t, 4));
      t = fmaxf(t, __shfl_xor(t, 8));
      mnew[r] = fmaxf(m_r[r], t);
      alpha[r] = exp2f(m_r[r] - mnew[r]);
      m_r[r] = mnew[r];
      psum[r] = 0.f;
    }
    // ---- P = 2^(S-m) -> Ps (stride 72), row sums ----
#pragma unroll
    for (int nt = 0; nt < 4; ++nt)
#pragma unroll
      for (int r = 0; r < 4; ++r) {
        float p = exp2f(sv[nt][r] - mnew[r]);
        psum[r] += p;
        Ps[w][(quad * 4 + r) * 72 + nt * 16 + l16] = f2bf(p);
      }
#pragma unroll
    for (int r = 0; r < 4; ++r) {
      float t = psum[r];
      t += __shfl_xor(t, 1);
      t += __shfl_xor(t, 2);
      t += __shfl_xor(t, 4);
      t += __shfl_xor(t, 8);
      l_r[r] = l_r[r] * alpha[r] + t;
#pragma unroll
      for (int dt = 0; dt < 4; ++dt) o[dt][r] *= alpha[r];
    }
    // ---- O += P V (V^T in LDS, swizzled cols) ----
    bf16x8 ap0 = *(const bf16x8*)&Ps[w][l16 * 72 + quad * 8];
    bf16x8 ap1 = *(const bf16x8*)&Ps[w][l16 * 72 + 32 + quad * 8];
#pragma unroll
    for (int dt = 0; dt < 4; ++dt) {
      bf16x8 bv0 = *(const bf16x8*)&Vs[(dt * 16 + l16) * 64 + koA];
      bf16x8 bv1 = *(const bf16x8*)&Vs[(dt * 16 + l16) * 64 + koB];
      o[dt] = __builtin_amdgcn_mfma_f32_16x16x32_bf16(ap0, bv0, o[dt], 0, 0, 0);
      o[dt] = __builtin_amdgcn_mfma_f32_16x16x32_bf16(ap1, bv1, o[dt], 0, 0, 0);
    }
    __syncthreads();   // all waves done with Ks/Vs before next DMA
  }
  // ---- epilogue: fp32 unnormalized partial O + (m,l) stats ----
  const int pid = blockIdx.x;
#pragma unroll
  for (int r = 0; r < 4; ++r) {
    const int q = w * 16 + quad * 4 + r;
    if (l16 == 0) { Mst[pid * 64 + q] = m_r[r]; Lst[pid * 64 + q] = l_r[r]; }
#pragma unroll
    for (int dt = 0; dt < 4; ++dt)
      Opart[(size_t)pid * 4096 + q * 64 + dt * 16 + l16] = o[dt][r];
  }
}

// ---------------- combine split-K partials ----------------
__global__ __launch_bounds__(256) void attn_combine(const float* __restrict__ Opart,
                                                    const float* __restrict__ Mst,
                                                    const float* __restrict__ Lst,
                                                    u16* __restrict__ Out) {
  const int x = blockIdx.x;
  const int t = threadIdx.x;
  const int q = t >> 2, db = (t & 3) * 16;
  const int b = x >> 7, h = (x >> 3) & 15, qt = x & 7;
  float ms[SPLIT], ls[SPLIT];
#pragma unroll
  for (int s = 0; s < SPLIT; ++s) {
    ms[s] = Mst[(size_t)(x * SPLIT + s) * 64 + q];
    ls[s] = Lst[(size_t)(x * SPLIT + s) * 64 + q];
  }
  float M = fmaxf(fmaxf(ms[0], ms[1]), fmaxf(ms[2], ms[3]));
  float wgt[SPLIT], L = 0.f;
#pragma unroll
  for (int s = 0; s < SPLIT; ++s) { wgt[s] = exp2f(ms[s] - M); L += wgt[s] * ls[s]; }
  const float inv = 1.0f / L;
  float acc[16] = {};
#pragma unroll
  for (int s = 0; s < SPLIT; ++s) {
    const float4* p = (const float4*)&Opart[(size_t)(x * SPLIT + s) * 4096 + q * 64 + db];
    const float ws = wgt[s];
#pragma unroll
    for (int i = 0; i < 4; ++i) {
      float4 v = p[i];
      acc[i * 4 + 0] += ws * v.x; acc[i * 4 + 1] += ws * v.y;
      acc[i * 4 + 2] += ws * v.z; acc[i * 4 + 3] += ws * v.w;
    }
  }
  union { u16 s[16]; uint4 v[2]; } ou;
#pragma unroll
  for (int i = 0; i < 16; ++i) ou.s[i] = f2bf(acc[i] * inv);
  u16* dst = Out + ((size_t)(b * NQ + qt * 64 + q)) * INNER + h * DH + db;
  *(uint4*)dst = ou.v[0]; *(uint4*)(dst + 8) = ou.v[1];
}

// ---------------- launcher ----------------
extern "C" void kernel_launch(void* const* d_in, const int* in_sizes, int n_in,
                              void* d_out, int out_size, void* d_ws, size_t ws_size,
                              hipStream_t stream) {
  const float* q    = (const float*)d_in[0];
  const float* kv   = (const float*)d_in[1];
  const int*   mask = (const int*)d_in[2];
  const float* Wq   = (const float*)d_in[3];
  const float* Wkv  = (const float*)d_in[4];
  const float* Wo   = (const float*)d_in[5];
  const float* bo   = (const float*)d_in[6];
  float* out = (float*)d_out;

  char* ws = (char*)d_ws;
  // [0,2):   qb  -> Mst/Lst after q-proj
  // [2,18):  kvb -> vT after kv-proj
  // [18,20): Wqt   [20,24): Wkvt   [24,26): Wot   [26,28): qh
  // [28,44): Kb    [44,60): Vb -> Opart (fp32) after vtrans
  // [60,62): attn
  u16*   qb    = (u16*)(ws);
  u16*   kvb   = (u16*)(ws + (2u << 20));
  float* Mst   = (float*)(ws);
  float* Lst   = (float*)(ws + (256u << 10));
  u16*   vT    = (u16*)(ws + (2u << 20));
  u16* Wqt  = (u16*)(ws + (18u << 20));
  u16* Wkvt = (u16*)(ws + (20u << 20));
  u16* Wot  = (u16*)(ws + (24u << 20));
  u16* qh   = (u16*)(ws + (26u << 20));
  u16* Kb   = (u16*)(ws + (28u << 20));
  u16* Vb   = (u16*)(ws + (44u << 20));
  float* Opart = (float*)(ws + (44u << 20));
  u16* attn = (u16*)(ws + (60u << 20));

  // fused conversions + weight transposes
  prep<<<dim3(8704), 256, 0, stream>>>(q, kv, Wq, Wkv, Wo, qb, kvb, Wqt, Wkvt, Wot);
  // qh = qb @ Wq (1024x1024x1024)
  gemm64<true><<<dim3(INNER / 64, (BATCH * NQ) / 64), 256, 0, stream>>>(
      qb, Wqt, nullptr, qh, nullptr, BATCH * NQ, INNER, DMODEL);
  // K/V projections -> split buffers [token][1024]
  gemm_kv<<<dim3(16, 64), 256, 0, stream>>>(kvb, Wkvt, Kb, Vb);
  // V^T [b][h][d][token]
  vtrans<<<dim3(BATCH * HEADS * (NKV / 64)), 256, 0, stream>>>(Vb, vT);
  // attention: split-K partials (DMA staging) + combine
  attn_part<<<dim3(BATCH * HEADS * (NQ / 64) * SPLIT), 256, 0, stream>>>(
      qh, Kb, vT, mask, Opart, Mst, Lst);
  attn_combine<<<dim3(BATCH * HEADS * (NQ / 64)), 256, 0, stream>>>(Opart, Mst, Lst, attn);
  // out = attn @ Wo + bo (fp32)
  gemm64<false><<<dim3(DMODEL / 64, (BATCH * NQ) / 64), 256, 0, stream>>>(
      attn, Wot, out, nullptr, bo, BATCH * NQ, DMODEL, INNER);
}

// Round 9
// 247.686 us; speedup vs baseline: 1.3464x; 1.0004x over previous
//
#include <hip/hip_runtime.h>
#include <string.h>
#include <math.h>

typedef unsigned short u16;
typedef __bf16 bf16x8 __attribute__((ext_vector_type(8)));
typedef float floatx4 __attribute__((ext_vector_type(4)));

#define HEADS  16
#define DH     64
#define BATCH  2
#define NQ     512
#define NKV    4096
#define DMODEL 1024
#define INNER  1024
#define SCALE  0.125f
#define LOG2E  1.4426950408889634f
#define SPLIT  4
#define KEYS_PER_PART (NKV / SPLIT)
#define CH (KEYS_PER_PART / 64)

__device__ __forceinline__ u16 f2bf(float f) {
  // native convert (v_cvt_*_bf16 on gfx950); RNE per HW
  union { __bf16 h; u16 u; } v; v.h = (__bf16)f; return v.u;
}

// async global->LDS, 16B per lane; LDS dest = wave-uniform base + lane*16
__device__ __forceinline__ void gll16(const u16* g, u16* l) {
  __builtin_amdgcn_global_load_lds(
      (const __attribute__((address_space(1))) unsigned int*)g,
      (__attribute__((address_space(3))) unsigned int*)l, 16, 0, 0);
}

// ---------------- fused prep: conv q, conv kv, transpose Wq/Wkv/Wo --------
__global__ __launch_bounds__(256) void prep(const float* __restrict__ q,
                                            const float* __restrict__ kv,
                                            const float* __restrict__ Wq,
                                            const float* __restrict__ Wkv,
                                            const float* __restrict__ Wo,
                                            u16* __restrict__ qb,
                                            u16* __restrict__ kvb,
                                            u16* __restrict__ Wqt,
                                            u16* __restrict__ Wkvt,
                                            u16* __restrict__ Wot) {
  __shared__ float tile[32][33];
  const int bx = blockIdx.x, tid = threadIdx.x;
  if (bx < 4608) {           // conv paths: 512 blocks q, 4096 blocks kv
    const float* x; u16* y; size_t i;
    if (bx < 512) { x = q;  y = qb;  i = (size_t)bx * 256 + tid; }
    else          { x = kv; y = kvb; i = (size_t)(bx - 512) * 256 + tid; }
    const float4* p = (const float4*)x + i * 2;
    float4 a = p[0], b = p[1];
    union { u16 s[8]; uint4 v; } o;
    o.s[0] = f2bf(a.x); o.s[1] = f2bf(a.y); o.s[2] = f2bf(a.z); o.s[3] = f2bf(a.w);
    o.s[4] = f2bf(b.x); o.s[5] = f2bf(b.y); o.s[6] = f2bf(b.z); o.s[7] = f2bf(b.w);
    *(uint4*)(y + i * 8) = o.v;
    return;
  }
  // transpose paths: Wt[n][k] = bf16(W[k][n])
  const float* W; u16* Wt; int K, N, n0, k0, t;
  if (bx < 5632)      { t = bx - 4608; W = Wq;  Wt = Wqt;  K = 1024; N = 1024; n0 = (t & 31) * 32; k0 = (t >> 5) * 32; }
  else if (bx < 7680) { t = bx - 5632; W = Wkv; Wt = Wkvt; K = 1024; N = 2048; n0 = (t & 63) * 32; k0 = (t >> 6) * 32; }
  else                { t = bx - 7680; W = Wo;  Wt = Wot;  K = 1024; N = 1024; n0 = (t & 31) * 32; k0 = (t >> 5) * 32; }
  const int tx = tid & 31, ty = tid >> 5;
  for (int i = 0; i < 32; i += 8)
    tile[ty + i][tx] = W[(size_t)(k0 + ty + i) * N + n0 + tx];
  __syncthreads();
  for (int i = 0; i < 32; i += 8)
    Wt[(size_t)(n0 + ty + i) * K + k0 + tx] = f2bf(tile[tx][ty + i]);
}

// ---------------- KV GEMM 128x128: writes K and V to separate buffers -----
__global__ __launch_bounds__(256) void gemm_kv(const u16* __restrict__ A,
                                               const u16* __restrict__ Bt,
                                               u16* __restrict__ Kb,
                                               u16* __restrict__ Vb) {
  const int K = DMODEL;
  __shared__ __align__(16) u16 As[128 * 32];
  __shared__ __align__(16) u16 Bs[128 * 32];
  const int tid  = threadIdx.x;
  const int lane = tid & 63, wave = tid >> 6;
  const int wr = wave >> 1, wc = wave & 1;
  const int l16 = lane & 15, quad = lane >> 4;
  const int bm = blockIdx.y, bn = blockIdx.x;
  const int r0 = tid >> 2;
  const int kb = (tid & 3) ^ ((tid >> 3) & 3);
  const u16* aP0 = A  + ((size_t)bm * 128 + r0)      * K + kb * 8;
  const u16* aP1 = A  + ((size_t)bm * 128 + r0 + 64) * K + kb * 8;
  const u16* bP0 = Bt + ((size_t)bn * 128 + r0)      * K + kb * 8;
  const u16* bP1 = Bt + ((size_t)bn * 128 + r0 + 64) * K + kb * 8;
  u16* ldsA0 = As + wave * 512;
  u16* ldsA1 = As + 2048 + wave * 512;
  u16* ldsB0 = Bs + wave * 512;
  u16* ldsB1 = Bs + 2048 + wave * 512;
  const int ko = ((quad ^ ((l16 >> 1) & 3)) << 3);

  floatx4 acc[4][4] = {};
  for (int k0 = 0; k0 < K; k0 += 32) {
    gll16(aP0 + k0, ldsA0);
    gll16(aP1 + k0, ldsA1);
    gll16(bP0 + k0, ldsB0);
    gll16(bP1 + k0, ldsB1);
    __syncthreads();
    bf16x8 af[4], bfr[4];
#pragma unroll
    for (int i = 0; i < 4; ++i)
      af[i] = *(const bf16x8*)&As[(wr * 64 + i * 16 + l16) * 32 + ko];
#pragma unroll
    for (int j = 0; j < 4; ++j)
      bfr[j] = *(const bf16x8*)&Bs[(wc * 64 + j * 16 + l16) * 32 + ko];
#pragma unroll
    for (int i = 0; i < 4; ++i)
#pragma unroll
      for (int j = 0; j < 4; ++j)
        acc[i][j] = __builtin_amdgcn_mfma_f32_16x16x32_bf16(af[i], bfr[j], acc[i][j], 0, 0, 0);
    __syncthreads();
  }
  u16* Cb = (bn < 8) ? Kb : Vb;
  const int colbase = ((bn < 8) ? bn : bn - 8) * 128;
#pragma unroll
  for (int i = 0; i < 4; ++i) {
    const int rowb = bm * 128 + wr * 64 + i * 16 + quad * 4;
#pragma unroll
    for (int j = 0; j < 4; ++j) {
      const int col = colbase + wc * 64 + j * 16 + l16;
#pragma unroll
      for (int r = 0; r < 4; ++r)
        Cb[(size_t)(rowb + r) * 1024 + col] = f2bf(acc[i][j][r]);
    }
  }
}

// ---------------- GEMM 64x64 tile (Q-proj / O-proj) ----------
template<bool OUT_BF16>
__global__ __launch_bounds__(256) void gemm64(const u16* __restrict__ A,
                                              const u16* __restrict__ Bt,
                                              float* __restrict__ Cf,
                                              u16* __restrict__ Cb,
                                              const float* __restrict__ bias,
                                              int M, int N, int K) {
  __shared__ __align__(16) u16 As[64 * 64];
  __shared__ __align__(16) u16 Bs[64 * 64];
  const int tid = threadIdx.x;
  const int lane = tid & 63, wave = tid >> 6;
  const int wr = wave >> 1, wc = wave & 1;
  const int l16 = lane & 15, quad = lane >> 4;
  const int bm = blockIdx.y, bn = blockIdx.x;
  const int r0 = tid >> 3;
  const int kbs = (tid & 7) ^ (r0 & 7);
  const u16* aP0 = A  + ((size_t)bm * 64 + r0)      * K + kbs * 8;
  const u16* aP1 = A  + ((size_t)bm * 64 + r0 + 32) * K + kbs * 8;
  const u16* bP0 = Bt + ((size_t)bn * 64 + r0)      * K + kbs * 8;
  const u16* bP1 = Bt + ((size_t)bn * 64 + r0 + 32) * K + kbs * 8;
  u16* ldsA0 = As + wave * 512;
  u16* ldsA1 = As + 2048 + wave * 512;
  u16* ldsB0 = Bs + wave * 512;
  u16* ldsB1 = Bs + 2048 + wave * 512;

  floatx4 acc[2][2] = {};
  for (int k0 = 0; k0 < K; k0 += 64) {
    gll16(aP0 + k0, ldsA0);
    gll16(aP1 + k0, ldsA1);
    gll16(bP0 + k0, ldsB0);
    gll16(bP1 + k0, ldsB1);
    __syncthreads();
    bf16x8 af[2][2], bfr[2][2];
#pragma unroll
    for (int i = 0; i < 2; ++i)
#pragma unroll
      for (int kk = 0; kk < 2; ++kk)
        af[i][kk] = *(const bf16x8*)&As[(wr * 32 + i * 16 + l16) * 64 +
                                        (((kk * 4 + quad) ^ (l16 & 7)) << 3)];
#pragma unroll
    for (int j = 0; j < 2; ++j)
#pragma unroll
      for (int kk = 0; kk < 2; ++kk)
        bfr[j][kk] = *(const bf16x8*)&Bs[(wc * 32 + j * 16 + l16) * 64 +
                                         (((kk * 4 + quad) ^ (l16 & 7)) << 3)];
#pragma unroll
    for (int i = 0; i < 2; ++i)
#pragma unroll
      for (int j = 0; j < 2; ++j) {
        acc[i][j] = __builtin_amdgcn_mfma_f32_16x16x32_bf16(af[i][0], bfr[j][0], acc[i][j], 0, 0, 0);
        acc[i][j] = __builtin_amdgcn_mfma_f32_16x16x32_bf16(af[i][1], bfr[j][1], acc[i][j], 0, 0, 0);
      }
    __syncthreads();
  }
#pragma unroll
  for (int i = 0; i < 2; ++i) {
    const int rowb = bm * 64 + wr * 32 + i * 16 + quad * 4;
#pragma unroll
    for (int j = 0; j < 2; ++j) {
      const int col = bn * 64 + wc * 32 + j * 16 + l16;
#pragma unroll
      for (int r = 0; r < 4; ++r) {
        const size_t idx = (size_t)(rowb + r) * N + col;
        if (OUT_BF16) Cb[idx] = f2bf(acc[i][j][r]);
        else          Cf[idx] = acc[i][j][r] + bias[col];
      }
    }
  }
}

// ---------------- V transpose: Vb[token][1024] -> vT[b][h][d][4096] -------
__global__ __launch_bounds__(256) void vtrans(const u16* __restrict__ Vb,
                                              u16* __restrict__ vT) {
  __shared__ u16 t[64 * 72];
  const int bx = blockIdx.x, tid = threadIdx.x;
  const int bh = bx >> 6, tb = bx & 63;      // bh = b*16+h, tb = 64-token block
  const int b = bh >> 4, h = bh & 15;
  const int r = tid >> 2, cg = (tid & 3) * 16;
  const u16* src = Vb + ((size_t)(b * NKV + tb * 64 + r)) * 1024 + h * 64 + cg;
  *(uint4*)&t[r * 72 + cg]     = ((const uint4*)src)[0];
  *(uint4*)&t[r * 72 + cg + 8] = ((const uint4*)src)[1];
  __syncthreads();
  const int d = tid >> 2, tg = (tid & 3) * 16;
  union { u16 s[16]; uint4 v[2]; } o;
#pragma unroll
  for (int i = 0; i < 16; ++i) o.s[i] = t[(tg + i) * 72 + d];
  u16* dst = vT + ((size_t)(bh * 64 + d)) * NKV + tb * 64 + tg;
  *(uint4*)dst = o.v[0]; *(uint4*)(dst + 8) = o.v[1];
}

// ---------------- flash attention, split-K partials (pipelined DMA) ------
// 4 waves; block = (b,h,64-q tile, 1024-key part); wave owns 16 q.
// Loop: [QK+softmax -> barrier A -> DMA(c+1) -> PV(c) -> barrier B].
// K single-buffered (writers gated by barrier A); V double-buffered.
__global__ __launch_bounds__(256) void attn_part(const u16* __restrict__ Qh,
                                                 const u16* __restrict__ Kb,
                                                 const u16* __restrict__ vT,
                                                 const int* __restrict__ mask,
                                                 float* __restrict__ Opart,
                                                 float* __restrict__ Mst,
                                                 float* __restrict__ Lst) {
  __shared__ __align__(16) u16 Ks[64 * 64];
  __shared__ __align__(16) u16 Vs[2][64 * 64];  // V^T tiles: [d][key], dbuf
  __shared__ __align__(16) u16 QP[4608];        // union: Qs(64x72) / Ps(4 x 16 x 72)
  __shared__ float Msk[64];
  const int tid = threadIdx.x;
  const int lane = tid & 63, w = tid >> 6;
  const int l16 = lane & 15, quad = lane >> 4;
  const int part = blockIdx.x & (SPLIT - 1);
  const int qt = (blockIdx.x >> 2) & 7;
  const int h  = (blockIdx.x >> 5) & 15;
  const int b  = blockIdx.x >> 9;
  const int rs = tid >> 2, d0 = (tid & 3) * 16;
  u16* Ps = QP + w * 1152;                      // 16 rows * stride 72

  // DMA source mapping: inst row = wave*8 + (lane>>3) (+32), k-block = (lane&7)^(row&7)
  const int r8 = lane >> 3;
  const int kb8 = (lane & 7) ^ (r8 & 7);
  const int key00 = part * KEYS_PER_PART;
  const u16* kSrc = Kb + ((size_t)(b * NKV + key00 + w * 8 + r8)) * 1024 + h * DH + kb8 * 8;
  const u16* vSrc = vT + ((size_t)((b * 16 + h) * 64 + w * 8 + r8)) * NKV + key00 + kb8 * 8;
  u16* ldsK0 = Ks + w * 512;
  u16* ldsK1 = Ks + 2048 + w * 512;
  // read-side swizzled k-block offsets (row&7 == l16&7 for rows nt*16+l16)
  const int koA = (quad ^ (l16 & 7)) << 3;
  const int koB = ((quad + 4) ^ (l16 & 7)) << 3;

  { // stage Q tile (64 x 64), stride 72, into QP
    const uint4* p = (const uint4*)(Qh + ((size_t)(b * NQ + qt * 64 + rs)) * INNER + h * DH + d0);
    *(uint4*)&QP[rs * 72 + d0]     = p[0];
    *(uint4*)&QP[rs * 72 + d0 + 8] = p[1];
  }
  // preamble DMA: chunk 0
  gll16(kSrc, ldsK0);
  gll16(kSrc + 32768, ldsK1);
  gll16(vSrc, Vs[0] + w * 512);
  gll16(vSrc + (size_t)32 * NKV, Vs[0] + 2048 + w * 512);
  float mk0 = 0.f;
  if (tid < 64) mk0 = (mask[(size_t)b * NKV + key00 + tid] != 0) ? 0.0f : -1e30f;
  __syncthreads();                    // Q staged + chunk-0 DMA landed
  bf16x8 aq0 = *(const bf16x8*)&QP[(w * 16 + l16) * 72 + quad * 8];
  bf16x8 aq1 = *(const bf16x8*)&QP[(w * 16 + l16) * 72 + 32 + quad * 8];
  if (tid < 64) Msk[tid] = mk0;
  __syncthreads();                    // QP reusable as Ps; Msk(0) visible

  floatx4 o[4] = {};
  float m_r[4] = {-1e30f, -1e30f, -1e30f, -1e30f};
  float l_r[4] = {0.f, 0.f, 0.f, 0.f};

  for (int c = 0; c < CH; ++c) {
    const u16* Vcur = Vs[c & 1];
    // ---- S = Q K^T (16 q x 64 keys per wave) ----
    float sv[4][4];
#pragma unroll
    for (int nt = 0; nt < 4; ++nt) {
      bf16x8 b0 = *(const bf16x8*)&Ks[(nt * 16 + l16) * 64 + koA];
      bf16x8 b1 = *(const bf16x8*)&Ks[(nt * 16 + l16) * 64 + koB];
      floatx4 t = {0.f, 0.f, 0.f, 0.f};
      t = __builtin_amdgcn_mfma_f32_16x16x32_bf16(aq0, b0, t, 0, 0, 0);
      t = __builtin_amdgcn_mfma_f32_16x16x32_bf16(aq1, b1, t, 0, 0, 0);
      const float mk = Msk[nt * 16 + l16];
#pragma unroll
      for (int r = 0; r < 4; ++r) sv[nt][r] = t[r] * (SCALE * LOG2E) + mk;  // log2 domain
    }
    // ---- row stats ----
    float mnew[4], alpha[4], psum[4];
#pragma unroll
    for (int r = 0; r < 4; ++r) {
      float t = fmaxf(fmaxf(sv[0][r], sv[1][r]), fmaxf(sv[2][r], sv[3][r]));
      t = fmaxf(t, __shfl_xor(t, 1));
      t = fmaxf(t, __shfl_xor(t, 2));
      t = fmaxf(t, __shfl_xor(t, 4));
      t = fmaxf(t, __shfl_xor(t, 8));
      mnew[r] = fmaxf(m_r[r], t);
      alpha[r] = exp2f(m_r[r] - mnew[r]);
      m_r[r] = mnew[r];
      psum[r] = 0.f;
    }
    // ---- P = 2^(S-m) -> Ps (wave-private), row sums ----
#pragma unroll
    for (int nt = 0; nt < 4; ++nt)
#pragma unroll
      for (int r = 0; r < 4; ++r) {
        float p = exp2f(sv[nt][r] - mnew[r]);
        psum[r] += p;
        Ps[(quad * 4 + r) * 72 + nt * 16 + l16] = f2bf(p);
      }
#pragma unroll
    for (int r = 0; r < 4; ++r) {
      float t = psum[r];
      t += __shfl_xor(t, 1);
      t += __shfl_xor(t, 2);
      t += __shfl_xor(t, 4);
      t += __shfl_xor(t, 8);
      l_r[r] = l_r[r] * alpha[r] + t;
#pragma unroll
      for (int dt = 0; dt < 4; ++dt) o[dt][r] *= alpha[r];
    }
    __syncthreads();   // barrier A: all waves done reading Ks & Msk
    // ---- issue DMA for chunk c+1 (latency hidden by PV below) ----
    if (c + 1 < CH) {
      gll16(kSrc + (size_t)(c + 1) * 65536, ldsK0);
      gll16(kSrc + (size_t)(c + 1) * 65536 + 32768, ldsK1);
      u16* vdst = Vs[(c + 1) & 1];
      gll16(vSrc + (c + 1) * 64, vdst + w * 512);
      gll16(vSrc + (c + 1) * 64 + (size_t)32 * NKV, vdst + 2048 + w * 512);
      if (tid < 64)
        Msk[tid] = (mask[(size_t)b * NKV + key00 + (c + 1) * 64 + tid] != 0) ? 0.0f : -1e30f;
    }
    // ---- O += P V (V^T in LDS, swizzled cols) ----
    bf16x8 ap0 = *(const bf16x8*)&Ps[l16 * 72 + quad * 8];
    bf16x8 ap1 = *(const bf16x8*)&Ps[l16 * 72 + 32 + quad * 8];
#pragma unroll
    for (int dt = 0; dt < 4; ++dt) {
      bf16x8 bv0 = *(const bf16x8*)&Vcur[(dt * 16 + l16) * 64 + koA];
      bf16x8 bv1 = *(const bf16x8*)&Vcur[(dt * 16 + l16) * 64 + koB];
      o[dt] = __builtin_amdgcn_mfma_f32_16x16x32_bf16(ap0, bv0, o[dt], 0, 0, 0);
      o[dt] = __builtin_amdgcn_mfma_f32_16x16x32_bf16(ap1, bv1, o[dt], 0, 0, 0);
    }
    __syncthreads();   // barrier B: next chunk's K/V landed; Ps reusable
  }
  // ---- epilogue: fp32 unnormalized partial O + (m,l) stats ----
  const int pid = blockIdx.x;
#pragma unroll
  for (int r = 0; r < 4; ++r) {
    const int q = w * 16 + quad * 4 + r;
    if (l16 == 0) { Mst[pid * 64 + q] = m_r[r]; Lst[pid * 64 + q] = l_r[r]; }
#pragma unroll
    for (int dt = 0; dt < 4; ++dt)
      Opart[(size_t)pid * 4096 + q * 64 + dt * 16 + l16] = o[dt][r];
  }
}

// ---------------- combine split-K partials ----------------
__global__ __launch_bounds__(256) void attn_combine(const float* __restrict__ Opart,
                                                    const float* __restrict__ Mst,
                                                    const float* __restrict__ Lst,
                                                    u16* __restrict__ Out) {
  const int x = blockIdx.x;
  const int t = threadIdx.x;
  const int q = t >> 2, db = (t & 3) * 16;
  const int b = x >> 7, h = (x >> 3) & 15, qt = x & 7;
  float ms[SPLIT], ls[SPLIT];
#pragma unroll
  for (int s = 0; s < SPLIT; ++s) {
    ms[s] = Mst[(size_t)(x * SPLIT + s) * 64 + q];
    ls[s] = Lst[(size_t)(x * SPLIT + s) * 64 + q];
  }
  float M = fmaxf(fmaxf(ms[0], ms[1]), fmaxf(ms[2], ms[3]));
  float wgt[SPLIT], L = 0.f;
#pragma unroll
  for (int s = 0; s < SPLIT; ++s) { wgt[s] = exp2f(ms[s] - M); L += wgt[s] * ls[s]; }
  const float inv = 1.0f / L;
  float acc[16] = {};
#pragma unroll
  for (int s = 0; s < SPLIT; ++s) {
    const float4* p = (const float4*)&Opart[(size_t)(x * SPLIT + s) * 4096 + q * 64 + db];
    const float ws = wgt[s];
#pragma unroll
    for (int i = 0; i < 4; ++i) {
      float4 v = p[i];
      acc[i * 4 + 0] += ws * v.x; acc[i * 4 + 1] += ws * v.y;
      acc[i * 4 + 2] += ws * v.z; acc[i * 4 + 3] += ws * v.w;
    }
  }
  union { u16 s[16]; uint4 v[2]; } ou;
#pragma unroll
  for (int i = 0; i < 16; ++i) ou.s[i] = f2bf(acc[i] * inv);
  u16* dst = Out + ((size_t)(b * NQ + qt * 64 + q)) * INNER + h * DH + db;
  *(uint4*)dst = ou.v[0]; *(uint4*)(dst + 8) = ou.v[1];
}

// ---------------- launcher ----------------
extern "C" void kernel_launch(void* const* d_in, const int* in_sizes, int n_in,
                              void* d_out, int out_size, void* d_ws, size_t ws_size,
                              hipStream_t stream) {
  const float* q    = (const float*)d_in[0];
  const float* kv   = (const float*)d_in[1];
  const int*   mask = (const int*)d_in[2];
  const float* Wq   = (const float*)d_in[3];
  const float* Wkv  = (const float*)d_in[4];
  const float* Wo   = (const float*)d_in[5];
  const float* bo   = (const float*)d_in[6];
  float* out = (float*)d_out;

  char* ws = (char*)d_ws;
  // [0,2):   qb  -> Mst/Lst after q-proj
  // [2,18):  kvb -> vT after kv-proj
  // [18,20): Wqt   [20,24): Wkvt   [24,26): Wot   [26,28): qh
  // [28,44): Kb    [44,60): Vb -> Opart (fp32) after vtrans
  // [60,62): attn
  u16*   qb    = (u16*)(ws);
  u16*   kvb   = (u16*)(ws + (2u << 20));
  float* Mst   = (float*)(ws);
  float* Lst   = (float*)(ws + (256u << 10));
  u16*   vT    = (u16*)(ws + (2u << 20));
  u16* Wqt  = (u16*)(ws + (18u << 20));
  u16* Wkvt = (u16*)(ws + (20u << 20));
  u16* Wot  = (u16*)(ws + (24u << 20));
  u16* qh   = (u16*)(ws + (26u << 20));
  u16* Kb   = (u16*)(ws + (28u << 20));
  u16* Vb   = (u16*)(ws + (44u << 20));
  float* Opart = (float*)(ws + (44u << 20));
  u16* attn = (u16*)(ws + (60u << 20));

  // fused conversions + weight transposes
  prep<<<dim3(8704), 256, 0, stream>>>(q, kv, Wq, Wkv, Wo, qb, kvb, Wqt, Wkvt, Wot);
  // qh = qb @ Wq (1024x1024x1024)
  gemm64<true><<<dim3(INNER / 64, (BATCH * NQ) / 64), 256, 0, stream>>>(
      qb, Wqt, nullptr, qh, nullptr, BATCH * NQ, INNER, DMODEL);
  // K/V projections -> split buffers [token][1024]
  gemm_kv<<<dim3(16, 64), 256, 0, stream>>>(kvb, Wkvt, Kb, Vb);
  // V^T [b][h][d][token]
  vtrans<<<dim3(BATCH * HEADS * (NKV / 64)), 256, 0, stream>>>(Vb, vT);
  // attention: split-K partials (pipelined DMA staging) + combine
  attn_part<<<dim3(BATCH * HEADS * (NQ / 64) * SPLIT), 256, 0, stream>>>(
      qh, Kb, vT, mask, Opart, Mst, Lst);
  attn_combine<<<dim3(BATCH * HEADS * (NQ / 64)), 256, 0, stream>>>(Opart, Mst, Lst, attn);
  // out = attn @ Wo + bo (fp32)
  gemm64<false><<<dim3(DMODEL / 64, (BATCH * NQ) / 64), 256, 0, stream>>>(
      attn, Wot, out, nullptr, bo, BATCH * NQ, DMODEL, INNER);
}

// Round 10
// 226.514 us; speedup vs baseline: 1.4722x; 1.0935x over previous
//
#include <hip/hip_runtime.h>
#include <string.h>
#include <math.h>

typedef unsigned short u16;
typedef __bf16 bf16x8 __attribute__((ext_vector_type(8)));
typedef float floatx4 __attribute__((ext_vector_type(4)));

#define HEADS  16
#define DH     64
#define BATCH  2
#define NQ     512
#define NKV    4096
#define DMODEL 1024
#define INNER  1024
#define SCALE  0.125f
#define LOG2E  1.4426950408889634f
#define FM     12.0f     // fixed softmax shift (log2 domain); |sv| < ~8 w.h.p.
#define SPLIT  4
#define KEYS_PER_PART (NKV / SPLIT)
#define CH (KEYS_PER_PART / 64)

__device__ __forceinline__ u16 f2bf(float f) {
  union { __bf16 h; u16 u; } v; v.h = (__bf16)f; return v.u;
}

// async global->LDS, 16B per lane; LDS dest = wave-uniform base + lane*16
__device__ __forceinline__ void gll16(const u16* g, u16* l) {
  __builtin_amdgcn_global_load_lds(
      (const __attribute__((address_space(1))) unsigned int*)g,
      (__attribute__((address_space(3))) unsigned int*)l, 16, 0, 0);
}

// ---------------- fused prep: conv q, conv kv, transpose Wq/Wkv/Wo --------
__global__ __launch_bounds__(256) void prep(const float* __restrict__ q,
                                            const float* __restrict__ kv,
                                            const float* __restrict__ Wq,
                                            const float* __restrict__ Wkv,
                                            const float* __restrict__ Wo,
                                            u16* __restrict__ qb,
                                            u16* __restrict__ kvb,
                                            u16* __restrict__ Wqt,
                                            u16* __restrict__ Wkvt,
                                            u16* __restrict__ Wot) {
  __shared__ float tile[32][33];
  const int bx = blockIdx.x, tid = threadIdx.x;
  if (bx < 4608) {           // conv paths: 512 blocks q, 4096 blocks kv
    const float* x; u16* y; size_t i;
    if (bx < 512) { x = q;  y = qb;  i = (size_t)bx * 256 + tid; }
    else          { x = kv; y = kvb; i = (size_t)(bx - 512) * 256 + tid; }
    const float4* p = (const float4*)x + i * 2;
    float4 a = p[0], b = p[1];
    union { u16 s[8]; uint4 v; } o;
    o.s[0] = f2bf(a.x); o.s[1] = f2bf(a.y); o.s[2] = f2bf(a.z); o.s[3] = f2bf(a.w);
    o.s[4] = f2bf(b.x); o.s[5] = f2bf(b.y); o.s[6] = f2bf(b.z); o.s[7] = f2bf(b.w);
    *(uint4*)(y + i * 8) = o.v;
    return;
  }
  // transpose paths: Wt[n][k] = bf16(W[k][n])
  const float* W; u16* Wt; int K, N, n0, k0, t;
  if (bx < 5632)      { t = bx - 4608; W = Wq;  Wt = Wqt;  K = 1024; N = 1024; n0 = (t & 31) * 32; k0 = (t >> 5) * 32; }
  else if (bx < 7680) { t = bx - 5632; W = Wkv; Wt = Wkvt; K = 1024; N = 2048; n0 = (t & 63) * 32; k0 = (t >> 6) * 32; }
  else                { t = bx - 7680; W = Wo;  Wt = Wot;  K = 1024; N = 1024; n0 = (t & 31) * 32; k0 = (t >> 5) * 32; }
  const int tx = tid & 31, ty = tid >> 5;
  for (int i = 0; i < 32; i += 8)
    tile[ty + i][tx] = W[(size_t)(k0 + ty + i) * N + n0 + tx];
  __syncthreads();
  for (int i = 0; i < 32; i += 8)
    Wt[(size_t)(n0 + ty + i) * K + k0 + tx] = f2bf(tile[tx][ty + i]);
}

// ---------------- KV GEMM 128x128: writes K and V to separate buffers -----
__global__ __launch_bounds__(256) void gemm_kv(const u16* __restrict__ A,
                                               const u16* __restrict__ Bt,
                                               u16* __restrict__ Kb,
                                               u16* __restrict__ Vb) {
  const int K = DMODEL;
  __shared__ __align__(16) u16 As[128 * 32];
  __shared__ __align__(16) u16 Bs[128 * 32];
  const int tid  = threadIdx.x;
  const int lane = tid & 63, wave = tid >> 6;
  const int wr = wave >> 1, wc = wave & 1;
  const int l16 = lane & 15, quad = lane >> 4;
  const int bm = blockIdx.y, bn = blockIdx.x;
  const int r0 = tid >> 2;
  const int kb = (tid & 3) ^ ((tid >> 3) & 3);
  const u16* aP0 = A  + ((size_t)bm * 128 + r0)      * K + kb * 8;
  const u16* aP1 = A  + ((size_t)bm * 128 + r0 + 64) * K + kb * 8;
  const u16* bP0 = Bt + ((size_t)bn * 128 + r0)      * K + kb * 8;
  const u16* bP1 = Bt + ((size_t)bn * 128 + r0 + 64) * K + kb * 8;
  u16* ldsA0 = As + wave * 512;
  u16* ldsA1 = As + 2048 + wave * 512;
  u16* ldsB0 = Bs + wave * 512;
  u16* ldsB1 = Bs + 2048 + wave * 512;
  const int ko = ((quad ^ ((l16 >> 1) & 3)) << 3);

  floatx4 acc[4][4] = {};
  for (int k0 = 0; k0 < K; k0 += 32) {
    gll16(aP0 + k0, ldsA0);
    gll16(aP1 + k0, ldsA1);
    gll16(bP0 + k0, ldsB0);
    gll16(bP1 + k0, ldsB1);
    __syncthreads();
    bf16x8 af[4], bfr[4];
#pragma unroll
    for (int i = 0; i < 4; ++i)
      af[i] = *(const bf16x8*)&As[(wr * 64 + i * 16 + l16) * 32 + ko];
#pragma unroll
    for (int j = 0; j < 4; ++j)
      bfr[j] = *(const bf16x8*)&Bs[(wc * 64 + j * 16 + l16) * 32 + ko];
#pragma unroll
    for (int i = 0; i < 4; ++i)
#pragma unroll
      for (int j = 0; j < 4; ++j)
        acc[i][j] = __builtin_amdgcn_mfma_f32_16x16x32_bf16(af[i], bfr[j], acc[i][j], 0, 0, 0);
    __syncthreads();
  }
  u16* Cb = (bn < 8) ? Kb : Vb;
  const int colbase = ((bn < 8) ? bn : bn - 8) * 128;
#pragma unroll
  for (int i = 0; i < 4; ++i) {
    const int rowb = bm * 128 + wr * 64 + i * 16 + quad * 4;
#pragma unroll
    for (int j = 0; j < 4; ++j) {
      const int col = colbase + wc * 64 + j * 16 + l16;
#pragma unroll
      for (int r = 0; r < 4; ++r)
        Cb[(size_t)(rowb + r) * 1024 + col] = f2bf(acc[i][j][r]);
    }
  }
}

// ---------------- GEMM 64x64 tile (Q-proj / O-proj) ----------
template<bool OUT_BF16>
__global__ __launch_bounds__(256) void gemm64(const u16* __restrict__ A,
                                              const u16* __restrict__ Bt,
                                              float* __restrict__ Cf,
                                              u16* __restrict__ Cb,
                                              const float* __restrict__ bias,
                                              int M, int N, int K) {
  __shared__ __align__(16) u16 As[64 * 64];
  __shared__ __align__(16) u16 Bs[64 * 64];
  const int tid = threadIdx.x;
  const int lane = tid & 63, wave = tid >> 6;
  const int wr = wave >> 1, wc = wave & 1;
  const int l16 = lane & 15, quad = lane >> 4;
  const int bm = blockIdx.y, bn = blockIdx.x;
  const int r0 = tid >> 3;
  const int kbs = (tid & 7) ^ (r0 & 7);
  const u16* aP0 = A  + ((size_t)bm * 64 + r0)      * K + kbs * 8;
  const u16* aP1 = A  + ((size_t)bm * 64 + r0 + 32) * K + kbs * 8;
  const u16* bP0 = Bt + ((size_t)bn * 64 + r0)      * K + kbs * 8;
  const u16* bP1 = Bt + ((size_t)bn * 64 + r0 + 32) * K + kbs * 8;
  u16* ldsA0 = As + wave * 512;
  u16* ldsA1 = As + 2048 + wave * 512;
  u16* ldsB0 = Bs + wave * 512;
  u16* ldsB1 = Bs + 2048 + wave * 512;

  floatx4 acc[2][2] = {};
  for (int k0 = 0; k0 < K; k0 += 64) {
    gll16(aP0 + k0, ldsA0);
    gll16(aP1 + k0, ldsA1);
    gll16(bP0 + k0, ldsB0);
    gll16(bP1 + k0, ldsB1);
    __syncthreads();
    bf16x8 af[2][2], bfr[2][2];
#pragma unroll
    for (int i = 0; i < 2; ++i)
#pragma unroll
      for (int kk = 0; kk < 2; ++kk)
        af[i][kk] = *(const bf16x8*)&As[(wr * 32 + i * 16 + l16) * 64 +
                                        (((kk * 4 + quad) ^ (l16 & 7)) << 3)];
#pragma unroll
    for (int j = 0; j < 2; ++j)
#pragma unroll
      for (int kk = 0; kk < 2; ++kk)
        bfr[j][kk] = *(const bf16x8*)&Bs[(wc * 32 + j * 16 + l16) * 64 +
                                         (((kk * 4 + quad) ^ (l16 & 7)) << 3)];
#pragma unroll
    for (int i = 0; i < 2; ++i)
#pragma unroll
      for (int j = 0; j < 2; ++j) {
        acc[i][j] = __builtin_amdgcn_mfma_f32_16x16x32_bf16(af[i][0], bfr[j][0], acc[i][j], 0, 0, 0);
        acc[i][j] = __builtin_amdgcn_mfma_f32_16x16x32_bf16(af[i][1], bfr[j][1], acc[i][j], 0, 0, 0);
      }
    __syncthreads();
  }
#pragma unroll
  for (int i = 0; i < 2; ++i) {
    const int rowb = bm * 64 + wr * 32 + i * 16 + quad * 4;
#pragma unroll
    for (int j = 0; j < 2; ++j) {
      const int col = bn * 64 + wc * 32 + j * 16 + l16;
#pragma unroll
      for (int r = 0; r < 4; ++r) {
        const size_t idx = (size_t)(rowb + r) * N + col;
        if (OUT_BF16) Cb[idx] = f2bf(acc[i][j][r]);
        else          Cf[idx] = acc[i][j][r] + bias[col];
      }
    }
  }
}

// ---------------- V transpose: Vb[token][1024] -> vT[b][h][d][4096] -------
__global__ __launch_bounds__(256) void vtrans(const u16* __restrict__ Vb,
                                              u16* __restrict__ vT) {
  __shared__ u16 t[64 * 72];
  const int bx = blockIdx.x, tid = threadIdx.x;
  const int bh = bx >> 6, tb = bx & 63;
  const int b = bh >> 4, h = bh & 15;
  const int r = tid >> 2, cg = (tid & 3) * 16;
  const u16* src = Vb + ((size_t)(b * NKV + tb * 64 + r)) * 1024 + h * 64 + cg;
  *(uint4*)&t[r * 72 + cg]     = ((const uint4*)src)[0];
  *(uint4*)&t[r * 72 + cg + 8] = ((const uint4*)src)[1];
  __syncthreads();
  const int d = tid >> 2, tg = (tid & 3) * 16;
  union { u16 s[16]; uint4 v[2]; } o;
#pragma unroll
  for (int i = 0; i < 16; ++i) o.s[i] = t[(tg + i) * 72 + d];
  u16* dst = vT + ((size_t)(bh * 64 + d)) * NKV + tb * 64 + tg;
  *(uint4*)dst = o.v[0]; *(uint4*)(dst + 8) = o.v[1];
}

// ---------------- flash attention, split-K partials -----------------------
// Fixed-shift softmax (no online max): p = 2^(s*SC + mask - FM). o and l are
// purely linear accumulators; l computed by 2 extra MFMAs vs a ones-column.
__global__ __launch_bounds__(256) void attn_part(const u16* __restrict__ Qh,
                                                 const u16* __restrict__ Kb,
                                                 const u16* __restrict__ vT,
                                                 const int* __restrict__ mask,
                                                 float* __restrict__ Opart,
                                                 float* __restrict__ Mst,
                                                 float* __restrict__ Lst) {
  __shared__ __align__(16) u16 Ks[64 * 64];
  __shared__ __align__(16) u16 Vs[2][64 * 64];  // V^T tiles: [d][key], dbuf
  __shared__ __align__(16) u16 QP[4608];        // union: Qs(64x72) / Ps(4 x 16 x 72)
  __shared__ float Msk[64];
  const int tid = threadIdx.x;
  const int lane = tid & 63, w = tid >> 6;
  const int l16 = lane & 15, quad = lane >> 4;
  const int part = blockIdx.x & (SPLIT - 1);
  const int qt = (blockIdx.x >> 2) & 7;
  const int h  = (blockIdx.x >> 5) & 15;
  const int b  = blockIdx.x >> 9;
  const int rs = tid >> 2, d0 = (tid & 3) * 16;
  u16* Ps = QP + w * 1152;                      // 16 rows * stride 72

  // DMA source mapping
  const int r8 = lane >> 3;
  const int kb8 = (lane & 7) ^ (r8 & 7);
  const int key00 = part * KEYS_PER_PART;
  const u16* kSrc = Kb + ((size_t)(b * NKV + key00 + w * 8 + r8)) * 1024 + h * DH + kb8 * 8;
  const u16* vSrc = vT + ((size_t)((b * 16 + h) * 64 + w * 8 + r8)) * NKV + key00 + kb8 * 8;
  u16* ldsK0 = Ks + w * 512;
  u16* ldsK1 = Ks + 2048 + w * 512;
  const int koA = (quad ^ (l16 & 7)) << 3;
  const int koB = ((quad + 4) ^ (l16 & 7)) << 3;

  // ones-column B fragment: B[n=0][k]=1, else 0 -> D[m][0] = rowsum(A)
  bf16x8 bones;
  {
    union { u16 s[8]; bf16x8 v; } t1;
    const u16 o1 = (l16 == 0) ? (u16)0x3F80 : (u16)0;
#pragma unroll
    for (int i = 0; i < 8; ++i) t1.s[i] = o1;
    bones = t1.v;
  }

  { // stage Q tile (64 x 64), stride 72, into QP
    const uint4* p = (const uint4*)(Qh + ((size_t)(b * NQ + qt * 64 + rs)) * INNER + h * DH + d0);
    *(uint4*)&QP[rs * 72 + d0]     = p[0];
    *(uint4*)&QP[rs * 72 + d0 + 8] = p[1];
  }
  // preamble DMA: chunk 0
  gll16(kSrc, ldsK0);
  gll16(kSrc + 32768, ldsK1);
  gll16(vSrc, Vs[0] + w * 512);
  gll16(vSrc + (size_t)32 * NKV, Vs[0] + 2048 + w * 512);
  float mk0 = 0.f;
  if (tid < 64) mk0 = (mask[(size_t)b * NKV + key00 + tid] != 0) ? -FM : -1e30f;
  __syncthreads();
  bf16x8 aq0 = *(const bf16x8*)&QP[(w * 16 + l16) * 72 + quad * 8];
  bf16x8 aq1 = *(const bf16x8*)&QP[(w * 16 + l16) * 72 + 32 + quad * 8];
  if (tid < 64) Msk[tid] = mk0;
  __syncthreads();

  floatx4 o[4] = {};
  floatx4 lacc = {0.f, 0.f, 0.f, 0.f};   // row sums (valid on l16==0 lanes)
  const float SC = SCALE * LOG2E;

  for (int c = 0; c < CH; ++c) {
    const u16* Vcur = Vs[c & 1];
    // ---- S = Q K^T ; P = 2^(S*SC + mask - FM) -> Ps ----
#pragma unroll
    for (int nt = 0; nt < 4; ++nt) {
      bf16x8 b0 = *(const bf16x8*)&Ks[(nt * 16 + l16) * 64 + koA];
      bf16x8 b1 = *(const bf16x8*)&Ks[(nt * 16 + l16) * 64 + koB];
      floatx4 t = {0.f, 0.f, 0.f, 0.f};
      t = __builtin_amdgcn_mfma_f32_16x16x32_bf16(aq0, b0, t, 0, 0, 0);
      t = __builtin_amdgcn_mfma_f32_16x16x32_bf16(aq1, b1, t, 0, 0, 0);
      const float mk = Msk[nt * 16 + l16];
#pragma unroll
      for (int r = 0; r < 4; ++r)
        Ps[(quad * 4 + r) * 72 + nt * 16 + l16] = f2bf(exp2f(t[r] * SC + mk));
    }
    __syncthreads();   // barrier A: all waves done reading Ks & Msk
    // ---- issue DMA for chunk c+1 ----
    if (c + 1 < CH) {
      gll16(kSrc + (size_t)(c + 1) * 65536, ldsK0);
      gll16(kSrc + (size_t)(c + 1) * 65536 + 32768, ldsK1);
      u16* vdst = Vs[(c + 1) & 1];
      gll16(vSrc + (c + 1) * 64, vdst + w * 512);
      gll16(vSrc + (c + 1) * 64 + (size_t)32 * NKV, vdst + 2048 + w * 512);
      if (tid < 64)
        Msk[tid] = (mask[(size_t)b * NKV + key00 + (c + 1) * 64 + tid] != 0) ? -FM : -1e30f;
    }
    // ---- O += P V ; l += P * ones ----
    bf16x8 ap0 = *(const bf16x8*)&Ps[l16 * 72 + quad * 8];
    bf16x8 ap1 = *(const bf16x8*)&Ps[l16 * 72 + 32 + quad * 8];
    lacc = __builtin_amdgcn_mfma_f32_16x16x32_bf16(ap0, bones, lacc, 0, 0, 0);
    lacc = __builtin_amdgcn_mfma_f32_16x16x32_bf16(ap1, bones, lacc, 0, 0, 0);
#pragma unroll
    for (int dt = 0; dt < 4; ++dt) {
      bf16x8 bv0 = *(const bf16x8*)&Vcur[(dt * 16 + l16) * 64 + koA];
      bf16x8 bv1 = *(const bf16x8*)&Vcur[(dt * 16 + l16) * 64 + koB];
      o[dt] = __builtin_amdgcn_mfma_f32_16x16x32_bf16(ap0, bv0, o[dt], 0, 0, 0);
      o[dt] = __builtin_amdgcn_mfma_f32_16x16x32_bf16(ap1, bv1, o[dt], 0, 0, 0);
    }
    __syncthreads();   // barrier B: next chunk's K/V landed; Ps reusable
  }
  // ---- epilogue: fp32 unnormalized partial O + (m=FM, l) stats ----
  const int pid = blockIdx.x;
#pragma unroll
  for (int r = 0; r < 4; ++r) {
    const int q = w * 16 + quad * 4 + r;
    if (l16 == 0) { Mst[pid * 64 + q] = FM; Lst[pid * 64 + q] = lacc[r]; }
#pragma unroll
    for (int dt = 0; dt < 4; ++dt)
      Opart[(size_t)pid * 4096 + q * 64 + dt * 16 + l16] = o[dt][r];
  }
}

// ---------------- combine split-K partials ----------------
__global__ __launch_bounds__(256) void attn_combine(const float* __restrict__ Opart,
                                                    const float* __restrict__ Mst,
                                                    const float* __restrict__ Lst,
                                                    u16* __restrict__ Out) {
  const int x = blockIdx.x;
  const int t = threadIdx.x;
  const int q = t >> 2, db = (t & 3) * 16;
  const int b = x >> 7, h = (x >> 3) & 15, qt = x & 7;
  float ms[SPLIT], ls[SPLIT];
#pragma unroll
  for (int s = 0; s < SPLIT; ++s) {
    ms[s] = Mst[(size_t)(x * SPLIT + s) * 64 + q];
    ls[s] = Lst[(size_t)(x * SPLIT + s) * 64 + q];
  }
  float M = fmaxf(fmaxf(ms[0], ms[1]), fmaxf(ms[2], ms[3]));
  float wgt[SPLIT], L = 0.f;
#pragma unroll
  for (int s = 0; s < SPLIT; ++s) { wgt[s] = exp2f(ms[s] - M); L += wgt[s] * ls[s]; }
  const float inv = 1.0f / L;
  float acc[16] = {};
#pragma unroll
  for (int s = 0; s < SPLIT; ++s) {
    const float4* p = (const float4*)&Opart[(size_t)(x * SPLIT + s) * 4096 + q * 64 + db];
    const float ws = wgt[s];
#pragma unroll
    for (int i = 0; i < 4; ++i) {
      float4 v = p[i];
      acc[i * 4 + 0] += ws * v.x; acc[i * 4 + 1] += ws * v.y;
      acc[i * 4 + 2] += ws * v.z; acc[i * 4 + 3] += ws * v.w;
    }
  }
  union { u16 s[16]; uint4 v[2]; } ou;
#pragma unroll
  for (int i = 0; i < 16; ++i) ou.s[i] = f2bf(acc[i] * inv);
  u16* dst = Out + ((size_t)(b * NQ + qt * 64 + q)) * INNER + h * DH + db;
  *(uint4*)dst = ou.v[0]; *(uint4*)(dst + 8) = ou.v[1];
}

// ---------------- launcher ----------------
extern "C" void kernel_launch(void* const* d_in, const int* in_sizes, int n_in,
                              void* d_out, int out_size, void* d_ws, size_t ws_size,
                              hipStream_t stream) {
  const float* q    = (const float*)d_in[0];
  const float* kv   = (const float*)d_in[1];
  const int*   mask = (const int*)d_in[2];
  const float* Wq   = (const float*)d_in[3];
  const float* Wkv  = (const float*)d_in[4];
  const float* Wo   = (const float*)d_in[5];
  const float* bo   = (const float*)d_in[6];
  float* out = (float*)d_out;

  char* ws = (char*)d_ws;
  u16*   qb    = (u16*)(ws);
  u16*   kvb   = (u16*)(ws + (2u << 20));
  float* Mst   = (float*)(ws);
  float* Lst   = (float*)(ws + (256u << 10));
  u16*   vT    = (u16*)(ws + (2u << 20));
  u16* Wqt  = (u16*)(ws + (18u << 20));
  u16* Wkvt = (u16*)(ws + (20u << 20));
  u16* Wot  = (u16*)(ws + (24u << 20));
  u16* qh   = (u16*)(ws + (26u << 20));
  u16* Kb   = (u16*)(ws + (28u << 20));
  u16* Vb   = (u16*)(ws + (44u << 20));
  float* Opart = (float*)(ws + (44u << 20));
  u16* attn = (u16*)(ws + (60u << 20));

  // fused conversions + weight transposes
  prep<<<dim3(8704), 256, 0, stream>>>(q, kv, Wq, Wkv, Wo, qb, kvb, Wqt, Wkvt, Wot);
  // qh = qb @ Wq (1024x1024x1024)
  gemm64<true><<<dim3(INNER / 64, (BATCH * NQ) / 64), 256, 0, stream>>>(
      qb, Wqt, nullptr, qh, nullptr, BATCH * NQ, INNER, DMODEL);
  // K/V projections -> split buffers [token][1024]
  gemm_kv<<<dim3(16, 64), 256, 0, stream>>>(kvb, Wkvt, Kb, Vb);
  // V^T [b][h][d][token]
  vtrans<<<dim3(BATCH * HEADS * (NKV / 64)), 256, 0, stream>>>(Vb, vT);
  // attention: split-K partials (fixed-shift softmax) + combine
  attn_part<<<dim3(BATCH * HEADS * (NQ / 64) * SPLIT), 256, 0, stream>>>(
      qh, Kb, vT, mask, Opart, Mst, Lst);
  attn_combine<<<dim3(BATCH * HEADS * (NQ / 64)), 256, 0, stream>>>(Opart, Mst, Lst, attn);
  // out = attn @ Wo + bo (fp32)
  gemm64<false><<<dim3(DMODEL / 64, (BATCH * NQ) / 64), 256, 0, stream>>>(
      attn, Wot, out, nullptr, bo, BATCH * NQ, DMODEL, INNER);
}

// Round 11
// 213.433 us; speedup vs baseline: 1.5625x; 1.0613x over previous
//
#include <hip/hip_runtime.h>
#include <string.h>
#include <math.h>

typedef unsigned short u16;
typedef __bf16 bf16x8 __attribute__((ext_vector_type(8)));
typedef float floatx4 __attribute__((ext_vector_type(4)));

#define HEADS  16
#define DH     64
#define BATCH  2
#define NQ     512
#define NKV    4096
#define DMODEL 1024
#define INNER  1024
#define SCALE  0.125f
#define LOG2E  1.4426950408889634f
#define FM     12.0f     // fixed softmax shift (log2 domain); |sv| < ~8 w.h.p.
#define SPLIT  4
#define KEYS_PER_PART (NKV / SPLIT)
#define CH (KEYS_PER_PART / 64)

__device__ __forceinline__ u16 f2bf(float f) {
  union { __bf16 h; u16 u; } v; v.h = (__bf16)f; return v.u;
}

// async global->LDS, 16B per lane; LDS dest = wave-uniform base + lane*16
__device__ __forceinline__ void gll16(const u16* g, u16* l) {
  __builtin_amdgcn_global_load_lds(
      (const __attribute__((address_space(1))) unsigned int*)g,
      (__attribute__((address_space(3))) unsigned int*)l, 16, 0, 0);
}

// ---------------- fused prep: conv q, conv kv, transpose Wq/Wkv/Wo --------
__global__ __launch_bounds__(256) void prep(const float* __restrict__ q,
                                            const float* __restrict__ kv,
                                            const float* __restrict__ Wq,
                                            const float* __restrict__ Wkv,
                                            const float* __restrict__ Wo,
                                            u16* __restrict__ qb,
                                            u16* __restrict__ kvb,
                                            u16* __restrict__ Wqt,
                                            u16* __restrict__ Wkvt,
                                            u16* __restrict__ Wot) {
  __shared__ float tile[32][33];
  const int bx = blockIdx.x, tid = threadIdx.x;
  if (bx < 4608) {           // conv paths: 512 blocks q, 4096 blocks kv
    const float* x; u16* y; size_t i;
    if (bx < 512) { x = q;  y = qb;  i = (size_t)bx * 256 + tid; }
    else          { x = kv; y = kvb; i = (size_t)(bx - 512) * 256 + tid; }
    const float4* p = (const float4*)x + i * 2;
    float4 a = p[0], b = p[1];
    union { u16 s[8]; uint4 v; } o;
    o.s[0] = f2bf(a.x); o.s[1] = f2bf(a.y); o.s[2] = f2bf(a.z); o.s[3] = f2bf(a.w);
    o.s[4] = f2bf(b.x); o.s[5] = f2bf(b.y); o.s[6] = f2bf(b.z); o.s[7] = f2bf(b.w);
    *(uint4*)(y + i * 8) = o.v;
    return;
  }
  // transpose paths: Wt[n][k] = bf16(W[k][n])
  const float* W; u16* Wt; int K, N, n0, k0, t;
  if (bx < 5632)      { t = bx - 4608; W = Wq;  Wt = Wqt;  K = 1024; N = 1024; n0 = (t & 31) * 32; k0 = (t >> 5) * 32; }
  else if (bx < 7680) { t = bx - 5632; W = Wkv; Wt = Wkvt; K = 1024; N = 2048; n0 = (t & 63) * 32; k0 = (t >> 6) * 32; }
  else                { t = bx - 7680; W = Wo;  Wt = Wot;  K = 1024; N = 1024; n0 = (t & 31) * 32; k0 = (t >> 5) * 32; }
  const int tx = tid & 31, ty = tid >> 5;
  for (int i = 0; i < 32; i += 8)
    tile[ty + i][tx] = W[(size_t)(k0 + ty + i) * N + n0 + tx];
  __syncthreads();
  for (int i = 0; i < 32; i += 8)
    Wt[(size_t)(n0 + ty + i) * K + k0 + tx] = f2bf(tile[tx][ty + i]);
}

// ---------------- KV GEMM 128x128, BK=64; V written transposed -----------
// C[8192 x 2048] = A[8192x1024] * Wkvt[2048x1024]^T.
// bn<8 -> Kb[token][1024]; bn>=8 -> vT[b*1024+d][token in batch].
__global__ __launch_bounds__(256) void gemm_kv(const u16* __restrict__ A,
                                               const u16* __restrict__ Bt,
                                               u16* __restrict__ Kb,
                                               u16* __restrict__ vT) {
  const int K = DMODEL;
  __shared__ __align__(16) u16 As[128 * 64];
  __shared__ __align__(16) u16 Bs[128 * 64];
  const int tid  = threadIdx.x;
  const int lane = tid & 63, wave = tid >> 6;
  const int wr = wave >> 1, wc = wave & 1;
  const int l16 = lane & 15, quad = lane >> 4;
  const int bm = blockIdx.y, bn = blockIdx.x;
  // DMA mapping: inst p covers rows p*32 + wave*8 + (lane>>3); swizzled k-block
  const int r8 = lane >> 3;
  const int kb8 = (lane & 7) ^ r8;
  const u16* aP = A  + ((size_t)bm * 128 + wave * 8 + r8) * K + kb8 * 8;
  const u16* bP = Bt + ((size_t)bn * 128 + wave * 8 + r8) * K + kb8 * 8;

  floatx4 acc[4][4] = {};
  for (int k0 = 0; k0 < K; k0 += 64) {
#pragma unroll
    for (int p = 0; p < 4; ++p) {
      gll16(aP + (size_t)p * 32 * K + k0, As + p * 2048 + wave * 512);
      gll16(bP + (size_t)p * 32 * K + k0, Bs + p * 2048 + wave * 512);
    }
    __syncthreads();
    bf16x8 af[4][2], bfr[4][2];
#pragma unroll
    for (int i = 0; i < 4; ++i)
#pragma unroll
      for (int h2 = 0; h2 < 2; ++h2)
        af[i][h2] = *(const bf16x8*)&As[(wr * 64 + i * 16 + l16) * 64 +
                                        (((h2 * 4 + quad) ^ (l16 & 7)) << 3)];
#pragma unroll
    for (int j = 0; j < 4; ++j)
#pragma unroll
      for (int h2 = 0; h2 < 2; ++h2)
        bfr[j][h2] = *(const bf16x8*)&Bs[(wc * 64 + j * 16 + l16) * 64 +
                                         (((h2 * 4 + quad) ^ (l16 & 7)) << 3)];
#pragma unroll
    for (int i = 0; i < 4; ++i)
#pragma unroll
      for (int j = 0; j < 4; ++j) {
        acc[i][j] = __builtin_amdgcn_mfma_f32_16x16x32_bf16(af[i][0], bfr[j][0], acc[i][j], 0, 0, 0);
        acc[i][j] = __builtin_amdgcn_mfma_f32_16x16x32_bf16(af[i][1], bfr[j][1], acc[i][j], 0, 0, 0);
      }
    __syncthreads();
  }
  if (bn < 8) {
    // K path: [token][1024]
#pragma unroll
    for (int i = 0; i < 4; ++i) {
      const int rowb = bm * 128 + wr * 64 + i * 16 + quad * 4;
#pragma unroll
      for (int j = 0; j < 4; ++j) {
        const int col = bn * 128 + wc * 64 + j * 16 + l16;
#pragma unroll
        for (int r = 0; r < 4; ++r)
          Kb[(size_t)(rowb + r) * 1024 + col] = f2bf(acc[i][j][r]);
      }
    }
  } else {
    // V path: write transposed -> vT[(b*1024 + d)][token]; 4 tokens packed
    const int b = bm >> 5;
    const int tokb = (bm & 31) * 128;
#pragma unroll
    for (int i = 0; i < 4; ++i) {
      const int tok0 = tokb + wr * 64 + i * 16 + quad * 4;
#pragma unroll
      for (int j = 0; j < 4; ++j) {
        const int d = (bn - 8) * 128 + wc * 64 + j * 16 + l16;
        union { u16 s[4]; uint2 v; } pk;
#pragma unroll
        for (int r = 0; r < 4; ++r) pk.s[r] = f2bf(acc[i][j][r]);
        *(uint2*)(vT + ((size_t)(b * 1024 + d)) * NKV + tok0) = pk.v;
      }
    }
  }
}

// ---------------- GEMM 64x64 tile (Q-proj / O-proj) ----------
template<bool OUT_BF16>
__global__ __launch_bounds__(256) void gemm64(const u16* __restrict__ A,
                                              const u16* __restrict__ Bt,
                                              float* __restrict__ Cf,
                                              u16* __restrict__ Cb,
                                              const float* __restrict__ bias,
                                              int M, int N, int K) {
  __shared__ __align__(16) u16 As[64 * 64];
  __shared__ __align__(16) u16 Bs[64 * 64];
  const int tid = threadIdx.x;
  const int lane = tid & 63, wave = tid >> 6;
  const int wr = wave >> 1, wc = wave & 1;
  const int l16 = lane & 15, quad = lane >> 4;
  const int bm = blockIdx.y, bn = blockIdx.x;
  const int r0 = tid >> 3;
  const int kbs = (tid & 7) ^ (r0 & 7);
  const u16* aP0 = A  + ((size_t)bm * 64 + r0)      * K + kbs * 8;
  const u16* aP1 = A  + ((size_t)bm * 64 + r0 + 32) * K + kbs * 8;
  const u16* bP0 = Bt + ((size_t)bn * 64 + r0)      * K + kbs * 8;
  const u16* bP1 = Bt + ((size_t)bn * 64 + r0 + 32) * K + kbs * 8;
  u16* ldsA0 = As + wave * 512;
  u16* ldsA1 = As + 2048 + wave * 512;
  u16* ldsB0 = Bs + wave * 512;
  u16* ldsB1 = Bs + 2048 + wave * 512;

  floatx4 acc[2][2] = {};
  for (int k0 = 0; k0 < K; k0 += 64) {
    gll16(aP0 + k0, ldsA0);
    gll16(aP1 + k0, ldsA1);
    gll16(bP0 + k0, ldsB0);
    gll16(bP1 + k0, ldsB1);
    __syncthreads();
    bf16x8 af[2][2], bfr[2][2];
#pragma unroll
    for (int i = 0; i < 2; ++i)
#pragma unroll
      for (int kk = 0; kk < 2; ++kk)
        af[i][kk] = *(const bf16x8*)&As[(wr * 32 + i * 16 + l16) * 64 +
                                        (((kk * 4 + quad) ^ (l16 & 7)) << 3)];
#pragma unroll
    for (int j = 0; j < 2; ++j)
#pragma unroll
      for (int kk = 0; kk < 2; ++kk)
        bfr[j][kk] = *(const bf16x8*)&Bs[(wc * 32 + j * 16 + l16) * 64 +
                                         (((kk * 4 + quad) ^ (l16 & 7)) << 3)];
#pragma unroll
    for (int i = 0; i < 2; ++i)
#pragma unroll
      for (int j = 0; j < 2; ++j) {
        acc[i][j] = __builtin_amdgcn_mfma_f32_16x16x32_bf16(af[i][0], bfr[j][0], acc[i][j], 0, 0, 0);
        acc[i][j] = __builtin_amdgcn_mfma_f32_16x16x32_bf16(af[i][1], bfr[j][1], acc[i][j], 0, 0, 0);
      }
    __syncthreads();
  }
#pragma unroll
  for (int i = 0; i < 2; ++i) {
    const int rowb = bm * 64 + wr * 32 + i * 16 + quad * 4;
#pragma unroll
    for (int j = 0; j < 2; ++j) {
      const int col = bn * 64 + wc * 32 + j * 16 + l16;
#pragma unroll
      for (int r = 0; r < 4; ++r) {
        const size_t idx = (size_t)(rowb + r) * N + col;
        if (OUT_BF16) Cb[idx] = f2bf(acc[i][j][r]);
        else          Cf[idx] = acc[i][j][r] + bias[col];
      }
    }
  }
}

// ---------------- flash attention, split-K partials -----------------------
// Fixed-shift softmax (no online max): p = 2^(s*SC + mask - FM). o and l are
// purely linear accumulators; l computed by 2 extra MFMAs vs a ones-column.
__global__ __launch_bounds__(256) void attn_part(const u16* __restrict__ Qh,
                                                 const u16* __restrict__ Kb,
                                                 const u16* __restrict__ vT,
                                                 const int* __restrict__ mask,
                                                 float* __restrict__ Opart,
                                                 float* __restrict__ Mst,
                                                 float* __restrict__ Lst) {
  __shared__ __align__(16) u16 Ks[64 * 64];
  __shared__ __align__(16) u16 Vs[2][64 * 64];  // V^T tiles: [d][key], dbuf
  __shared__ __align__(16) u16 QP[4608];        // union: Qs(64x72) / Ps(4 x 16 x 72)
  __shared__ float Msk[64];
  const int tid = threadIdx.x;
  const int lane = tid & 63, w = tid >> 6;
  const int l16 = lane & 15, quad = lane >> 4;
  const int part = blockIdx.x & (SPLIT - 1);
  const int qt = (blockIdx.x >> 2) & 7;
  const int h  = (blockIdx.x >> 5) & 15;
  const int b  = blockIdx.x >> 9;
  const int rs = tid >> 2, d0 = (tid & 3) * 16;
  u16* Ps = QP + w * 1152;                      // 16 rows * stride 72

  // DMA source mapping
  const int r8 = lane >> 3;
  const int kb8 = (lane & 7) ^ (r8 & 7);
  const int key00 = part * KEYS_PER_PART;
  const u16* kSrc = Kb + ((size_t)(b * NKV + key00 + w * 8 + r8)) * 1024 + h * DH + kb8 * 8;
  const u16* vSrc = vT + ((size_t)((b * 16 + h) * 64 + w * 8 + r8)) * NKV + key00 + kb8 * 8;
  u16* ldsK0 = Ks + w * 512;
  u16* ldsK1 = Ks + 2048 + w * 512;
  const int koA = (quad ^ (l16 & 7)) << 3;
  const int koB = ((quad + 4) ^ (l16 & 7)) << 3;

  // ones-column B fragment: B[n=0][k]=1, else 0 -> D[m][0] = rowsum(A)
  bf16x8 bones;
  {
    union { u16 s[8]; bf16x8 v; } t1;
    const u16 o1 = (l16 == 0) ? (u16)0x3F80 : (u16)0;
#pragma unroll
    for (int i = 0; i < 8; ++i) t1.s[i] = o1;
    bones = t1.v;
  }

  { // stage Q tile (64 x 64), stride 72, into QP
    const uint4* p = (const uint4*)(Qh + ((size_t)(b * NQ + qt * 64 + rs)) * INNER + h * DH + d0);
    *(uint4*)&QP[rs * 72 + d0]     = p[0];
    *(uint4*)&QP[rs * 72 + d0 + 8] = p[1];
  }
  // preamble DMA: chunk 0
  gll16(kSrc, ldsK0);
  gll16(kSrc + 32768, ldsK1);
  gll16(vSrc, Vs[0] + w * 512);
  gll16(vSrc + (size_t)32 * NKV, Vs[0] + 2048 + w * 512);
  float mk0 = 0.f;
  if (tid < 64) mk0 = (mask[(size_t)b * NKV + key00 + tid] != 0) ? -FM : -1e30f;
  __syncthreads();
  bf16x8 aq0 = *(const bf16x8*)&QP[(w * 16 + l16) * 72 + quad * 8];
  bf16x8 aq1 = *(const bf16x8*)&QP[(w * 16 + l16) * 72 + 32 + quad * 8];
  if (tid < 64) Msk[tid] = mk0;
  __syncthreads();

  floatx4 o[4] = {};
  floatx4 lacc = {0.f, 0.f, 0.f, 0.f};   // row sums (valid on l16==0 lanes)
  const float SC = SCALE * LOG2E;

  for (int c = 0; c < CH; ++c) {
    const u16* Vcur = Vs[c & 1];
    // ---- S = Q K^T ; P = 2^(S*SC + mask - FM) -> Ps ----
#pragma unroll
    for (int nt = 0; nt < 4; ++nt) {
      bf16x8 b0 = *(const bf16x8*)&Ks[(nt * 16 + l16) * 64 + koA];
      bf16x8 b1 = *(const bf16x8*)&Ks[(nt * 16 + l16) * 64 + koB];
      floatx4 t = {0.f, 0.f, 0.f, 0.f};
      t = __builtin_amdgcn_mfma_f32_16x16x32_bf16(aq0, b0, t, 0, 0, 0);
      t = __builtin_amdgcn_mfma_f32_16x16x32_bf16(aq1, b1, t, 0, 0, 0);
      const float mk = Msk[nt * 16 + l16];
#pragma unroll
      for (int r = 0; r < 4; ++r)
        Ps[(quad * 4 + r) * 72 + nt * 16 + l16] = f2bf(exp2f(t[r] * SC + mk));
    }
    __syncthreads();   // barrier A: all waves done reading Ks & Msk
    // ---- issue DMA for chunk c+1 ----
    if (c + 1 < CH) {
      gll16(kSrc + (size_t)(c + 1) * 65536, ldsK0);
      gll16(kSrc + (size_t)(c + 1) * 65536 + 32768, ldsK1);
      u16* vdst = Vs[(c + 1) & 1];
      gll16(vSrc + (c + 1) * 64, vdst + w * 512);
      gll16(vSrc + (c + 1) * 64 + (size_t)32 * NKV, vdst + 2048 + w * 512);
      if (tid < 64)
        Msk[tid] = (mask[(size_t)b * NKV + key00 + (c + 1) * 64 + tid] != 0) ? -FM : -1e30f;
    }
    // ---- O += P V ; l += P * ones ----
    bf16x8 ap0 = *(const bf16x8*)&Ps[l16 * 72 + quad * 8];
    bf16x8 ap1 = *(const bf16x8*)&Ps[l16 * 72 + 32 + quad * 8];
    lacc = __builtin_amdgcn_mfma_f32_16x16x32_bf16(ap0, bones, lacc, 0, 0, 0);
    lacc = __builtin_amdgcn_mfma_f32_16x16x32_bf16(ap1, bones, lacc, 0, 0, 0);
#pragma unroll
    for (int dt = 0; dt < 4; ++dt) {
      bf16x8 bv0 = *(const bf16x8*)&Vcur[(dt * 16 + l16) * 64 + koA];
      bf16x8 bv1 = *(const bf16x8*)&Vcur[(dt * 16 + l16) * 64 + koB];
      o[dt] = __builtin_amdgcn_mfma_f32_16x16x32_bf16(ap0, bv0, o[dt], 0, 0, 0);
      o[dt] = __builtin_amdgcn_mfma_f32_16x16x32_bf16(ap1, bv1, o[dt], 0, 0, 0);
    }
    __syncthreads();   // barrier B: next chunk's K/V landed; Ps reusable
  }
  // ---- epilogue: fp32 unnormalized partial O + (m=FM, l) stats ----
  const int pid = blockIdx.x;
#pragma unroll
  for (int r = 0; r < 4; ++r) {
    const int q = w * 16 + quad * 4 + r;
    if (l16 == 0) { Mst[pid * 64 + q] = FM; Lst[pid * 64 + q] = lacc[r]; }
#pragma unroll
    for (int dt = 0; dt < 4; ++dt)
      Opart[(size_t)pid * 4096 + q * 64 + dt * 16 + l16] = o[dt][r];
  }
}

// ---------------- combine split-K partials ----------------
__global__ __launch_bounds__(256) void attn_combine(const float* __restrict__ Opart,
                                                    const float* __restrict__ Mst,
                                                    const float* __restrict__ Lst,
                                                    u16* __restrict__ Out) {
  const int x = blockIdx.x;
  const int t = threadIdx.x;
  const int q = t >> 2, db = (t & 3) * 16;
  const int b = x >> 7, h = (x >> 3) & 15, qt = x & 7;
  float ms[SPLIT], ls[SPLIT];
#pragma unroll
  for (int s = 0; s < SPLIT; ++s) {
    ms[s] = Mst[(size_t)(x * SPLIT + s) * 64 + q];
    ls[s] = Lst[(size_t)(x * SPLIT + s) * 64 + q];
  }
  float M = fmaxf(fmaxf(ms[0], ms[1]), fmaxf(ms[2], ms[3]));
  float wgt[SPLIT], L = 0.f;
#pragma unroll
  for (int s = 0; s < SPLIT; ++s) { wgt[s] = exp2f(ms[s] - M); L += wgt[s] * ls[s]; }
  const float inv = 1.0f / L;
  float acc[16] = {};
#pragma unroll
  for (int s = 0; s < SPLIT; ++s) {
    const float4* p = (const float4*)&Opart[(size_t)(x * SPLIT + s) * 4096 + q * 64 + db];
    const float ws = wgt[s];
#pragma unroll
    for (int i = 0; i < 4; ++i) {
      float4 v = p[i];
      acc[i * 4 + 0] += ws * v.x; acc[i * 4 + 1] += ws * v.y;
      acc[i * 4 + 2] += ws * v.z; acc[i * 4 + 3] += ws * v.w;
    }
  }
  union { u16 s[16]; uint4 v[2]; } ou;
#pragma unroll
  for (int i = 0; i < 16; ++i) ou.s[i] = f2bf(acc[i] * inv);
  u16* dst = Out + ((size_t)(b * NQ + qt * 64 + q)) * INNER + h * DH + db;
  *(uint4*)dst = ou.v[0]; *(uint4*)(dst + 8) = ou.v[1];
}

// ---------------- launcher ----------------
extern "C" void kernel_launch(void* const* d_in, const int* in_sizes, int n_in,
                              void* d_out, int out_size, void* d_ws, size_t ws_size,
                              hipStream_t stream) {
  const float* q    = (const float*)d_in[0];
  const float* kv   = (const float*)d_in[1];
  const int*   mask = (const int*)d_in[2];
  const float* Wq   = (const float*)d_in[3];
  const float* Wkv  = (const float*)d_in[4];
  const float* Wo   = (const float*)d_in[5];
  const float* bo   = (const float*)d_in[6];
  float* out = (float*)d_out;

  char* ws = (char*)d_ws;
  // [0,2):   qb  -> Mst/Lst after q-proj
  // [2,18):  kvb -> Opart (fp32) after gemm_kv
  // [18,20): Wqt   [20,24): Wkvt   [24,26): Wot   [26,28): qh
  // [28,44): Kb    [44,60): vT    [60,62): attn
  u16*   qb    = (u16*)(ws);
  u16*   kvb   = (u16*)(ws + (2u << 20));
  float* Mst   = (float*)(ws);
  float* Lst   = (float*)(ws + (256u << 10));
  float* Opart = (float*)(ws + (2u << 20));
  u16* Wqt  = (u16*)(ws + (18u << 20));
  u16* Wkvt = (u16*)(ws + (20u << 20));
  u16* Wot  = (u16*)(ws + (24u << 20));
  u16* qh   = (u16*)(ws + (26u << 20));
  u16* Kb   = (u16*)(ws + (28u << 20));
  u16* vT   = (u16*)(ws + (44u << 20));
  u16* attn = (u16*)(ws + (60u << 20));

  // fused conversions + weight transposes
  prep<<<dim3(8704), 256, 0, stream>>>(q, kv, Wq, Wkv, Wo, qb, kvb, Wqt, Wkvt, Wot);
  // qh = qb @ Wq (1024x1024x1024)
  gemm64<true><<<dim3(INNER / 64, (BATCH * NQ) / 64), 256, 0, stream>>>(
      qb, Wqt, nullptr, qh, nullptr, BATCH * NQ, INNER, DMODEL);
  // K/V projections; V written pre-transposed for attention
  gemm_kv<<<dim3(16, 64), 256, 0, stream>>>(kvb, Wkvt, Kb, vT);
  // attention: split-K partials (fixed-shift softmax) + combine
  attn_part<<<dim3(BATCH * HEADS * (NQ / 64) * SPLIT), 256, 0, stream>>>(
      qh, Kb, vT, mask, Opart, Mst, Lst);
  attn_combine<<<dim3(BATCH * HEADS * (NQ / 64)), 256, 0, stream>>>(Opart, Mst, Lst, attn);
  // out = attn @ Wo + bo (fp32)
  gemm64<false><<<dim3(DMODEL / 64, (BATCH * NQ) / 64), 256, 0, stream>>>(
      attn, Wot, out, nullptr, bo, BATCH * NQ, DMODEL, INNER);
}